// Round 2
// baseline (925.285 us; speedup 1.0000x reference)
//
#include <hip/hip_runtime.h>
#include <hip/hip_bf16.h>

typedef unsigned short u16;
typedef unsigned int u32;

#define NEG_SLOPE 0.2f

__device__ __forceinline__ float bf2f(u16 u){
  union { u32 i; float f; } c; c.i = ((u32)u) << 16; return c.f;
}
__device__ __forceinline__ u16 f2bf(float f){
  __hip_bfloat16 h = __float2bfloat16(f);
  u16 u; __builtin_memcpy(&u, &h, 2); return u;
}
__device__ __forceinline__ float lrelu(float x){
  return fmaxf(x, 0.f) + NEG_SLOPE * fminf(x, 0.f);
}
__device__ __forceinline__ float eluf(float x){
  return x > 0.f ? x : (__expf(x) - 1.f);
}

// ---------------- dtype probe ----------------
// View W1s as u16. bf16 weights (|w| <= ~1) never have exponent-field >= 200.
// f32 weights viewed as u16 halves have random mantissa bits in the exponent
// field of even halves -> triggers with overwhelming probability.
__global__ void k_probe(const u16* __restrict__ w, int* __restrict__ flag){
  int t = threadIdx.x;
  int hit = 0;
  for (int i = t; i < 4096; i += 64){
    u16 v = w[i];
    int e = (v >> 7) & 0xFF;
    if (e >= 200) hit = 1;
  }
  unsigned long long b = __ballot(hit);
  if (t == 0) flag[0] = b ? 1 : 0;   // 1 => float32 data
}

// ---------------- param conversion to f32 arena ----------------
struct Params13 {
  const void* src[13];
  int off[13];
  int n[13];
};

__global__ void k_cvt(Params13 P, const int* __restrict__ flag, float* __restrict__ dst){
  int t = blockIdx.y;
  int i = blockIdx.x*256 + threadIdx.x;
  if (i >= P.n[t]) return;
  int f = flag[0];
  float v = f ? ((const float*)P.src[t])[i] : bf2f(((const u16*)P.src[t])[i]);
  dst[P.off[t] + i] = v;
}

// ---------------- CSR build ----------------
__global__ void k_deg(const int* __restrict__ dst, int* __restrict__ deg, int E){
  int i = blockIdx.x*256 + threadIdx.x;
  if (i < E) atomicAdd(&deg[dst[i]], 1);
}

__global__ void k_scan(const int* __restrict__ deg, int* __restrict__ rowptr,
                       int* __restrict__ cursor, int N){
  int l = threadIdx.x;  // 64 lanes
  int carry = 0;
  int nChunk = (N + 255) >> 8;
  for (int c = 0; c < nChunk; ++c){
    int idx = (c << 8) + l*4;
    int v0=0,v1=0,v2=0,v3=0;
    if (idx + 3 < N){
      const int4 v = *reinterpret_cast<const int4*>(deg + idx);
      v0=v.x; v1=v.y; v2=v.z; v3=v.w;
    } else {
      if (idx+0 < N) v0 = deg[idx+0];
      if (idx+1 < N) v1 = deg[idx+1];
      if (idx+2 < N) v2 = deg[idx+2];
      if (idx+3 < N) v3 = deg[idx+3];
    }
    int s1 = v0+v1, s2 = s1+v2, tot = s2+v3;
    int x = tot;
    #pragma unroll
    for (int off=1; off<64; off<<=1){
      int y = __shfl_up(x, off);
      if (l >= off) x += y;
    }
    int excl = carry + x - tot;
    if (idx+0 < N){ rowptr[idx+0]=excl;    cursor[idx+0]=excl;    }
    if (idx+1 < N){ rowptr[idx+1]=excl+v0; cursor[idx+1]=excl+v0; }
    if (idx+2 < N){ rowptr[idx+2]=excl+s1; cursor[idx+2]=excl+s1; }
    if (idx+3 < N){ rowptr[idx+3]=excl+s2; cursor[idx+3]=excl+s2; }
    carry += __shfl(x, 63);
  }
  if (l == 0) rowptr[N] = carry;
}

__global__ void k_scatter(const int* __restrict__ dst, int* __restrict__ cursor,
                          int* __restrict__ ecsr, int E){
  int i = blockIdx.x*256 + threadIdx.x;
  if (i < E){
    int d = dst[i];
    int pos = atomicAdd(&cursor[d], 1);
    ecsr[pos] = i;
  }
}

// ---------------- layer-1 tiny tables ----------------
// Ts[v][j] = sum_k emb[v][k]*W1s[k][j]; Td likewise (32x128 each)
__global__ void k_tinyA(const float* __restrict__ pr,
                        float* __restrict__ Ts, float* __restrict__ Td){
  const float* emb = pr + 0;
  const float* W1s = pr + 4096;
  const float* W1d = pr + 20480;
  int g = blockIdx.x*256 + threadIdx.x;   // 0..4095
  int v = g >> 7, j = g & 127;
  float as = 0.f, ad = 0.f;
  for (int k = 0; k < 128; ++k){
    float e = emb[v*128 + k];
    as += e * W1s[k*128 + j];
    ad += e * W1d[k*128 + j];
  }
  Ts[g] = as; Td[g] = ad;
}

// S1[vs][vd][h] = sum_d a1[h][d]*leaky(Ts[vs][h*32+d]+Td[vd][h*32+d])
__global__ void k_tinyB(const float* __restrict__ Ts, const float* __restrict__ Td,
                        const float* __restrict__ pr, float* __restrict__ S1){
  const float* a1 = pr + 36864;
  int g = blockIdx.x*256 + threadIdx.x;   // vs*128 + vd*4 + h
  int vs = g >> 7, vd = (g >> 2) & 31, h = g & 3;
  float acc = 0.f;
  for (int dd = 0; dd < 32; ++dd){
    float x = Ts[vs*128 + h*32 + dd] + Td[vd*128 + h*32 + dd];
    acc += a1[h*32 + dd] * lrelu(x);
  }
  S1[g] = acc;
}

// ---------------- node kernels (one wave per dst node) ----------------
__global__ __launch_bounds__(256) void k_node1(
    const int* __restrict__ rowptr, const int* __restrict__ ecsr, const int* __restrict__ src,
    const int* __restrict__ vf, const float* __restrict__ Ts, const float* __restrict__ S1,
    const float* __restrict__ pr, float* __restrict__ hOut, int N){
  const float* b1 = pr + 36992;
  __shared__ float TsL[4096];
  __shared__ float S1L[4096];
  int t = threadIdx.x;
  for (int i = t; i < 4096; i += 256){ TsL[i] = Ts[i]; S1L[i] = S1[i]; }
  __syncthreads();
  int wid = t >> 6, lane = t & 63;
  int d = blockIdx.x*4 + wid;
  if (d >= N) return;
  int r0 = rowptr[d], r1 = rowptr[d+1];
  int vfd = vf[d];
  float4 m = make_float4(-INFINITY,-INFINITY,-INFINITY,-INFINITY);
  for (int i = r0 + lane; i < r1; i += 64){
    int e = ecsr[i];
    int vs = vf[src[e]];
    const float4 sc = *reinterpret_cast<const float4*>(&S1L[(vs*32 + vfd)*4]);
    m.x = fmaxf(m.x, sc.x); m.y = fmaxf(m.y, sc.y);
    m.z = fmaxf(m.z, sc.z); m.w = fmaxf(m.w, sc.w);
  }
  #pragma unroll
  for (int off=1; off<64; off<<=1){
    m.x = fmaxf(m.x, __shfl_xor(m.x, off));
    m.y = fmaxf(m.y, __shfl_xor(m.y, off));
    m.z = fmaxf(m.z, __shfl_xor(m.z, off));
    m.w = fmaxf(m.w, __shfl_xor(m.w, off));
  }
  int h = lane >> 4;
  float mh = (h==0)?m.x:(h==1)?m.y:(h==2)?m.z:m.w;
  float ax = 0.f, ay = 0.f, ssum = 0.f;
  for (int i = r0; i < r1; ++i){
    int e = ecsr[i];
    int vs = vf[src[e]];
    float sc = S1L[(vs*32 + vfd)*4 + h];
    float ex = __expf(sc - mh);
    ssum += ex;
    const float2 f = *reinterpret_cast<const float2*>(&TsL[vs*128 + lane*2]);
    ax += ex * f.x; ay += ex * f.y;
  }
  float inv = (r1 > r0) ? 1.f/ssum : 0.f;
  float2 o;
  o.x = eluf(ax*inv + b1[lane*2]);
  o.y = eluf(ay*inv + b1[lane*2+1]);
  *reinterpret_cast<float2*>(&hOut[(size_t)d*128 + lane*2]) = o;
}

__global__ __launch_bounds__(256) void k_node2(
    const int* __restrict__ rowptr, const int* __restrict__ ecsr, const int* __restrict__ src,
    const float* __restrict__ score, const float* __restrict__ fs,
    const float* __restrict__ bias, float* __restrict__ hOut, int N){
  int t = threadIdx.x;
  int wid = t >> 6, lane = t & 63;
  int d = blockIdx.x*4 + wid;
  if (d >= N) return;
  int r0 = rowptr[d], r1 = rowptr[d+1];
  float4 m = make_float4(-INFINITY,-INFINITY,-INFINITY,-INFINITY);
  for (int i = r0 + lane; i < r1; i += 64){
    int e = ecsr[i];
    const float4 sc = *reinterpret_cast<const float4*>(score + (size_t)e*4);
    m.x=fmaxf(m.x,sc.x); m.y=fmaxf(m.y,sc.y); m.z=fmaxf(m.z,sc.z); m.w=fmaxf(m.w,sc.w);
  }
  #pragma unroll
  for (int off=1; off<64; off<<=1){
    m.x = fmaxf(m.x, __shfl_xor(m.x, off));
    m.y = fmaxf(m.y, __shfl_xor(m.y, off));
    m.z = fmaxf(m.z, __shfl_xor(m.z, off));
    m.w = fmaxf(m.w, __shfl_xor(m.w, off));
  }
  int h = lane >> 4;
  float mh = (h==0)?m.x:(h==1)?m.y:(h==2)?m.z:m.w;
  float ax=0.f, ay=0.f, ssum=0.f;
  for (int i = r0; i < r1; ++i){
    int e = ecsr[i];
    int s = src[e];
    float sc = score[(size_t)e*4 + h];
    float ex = __expf(sc - mh);
    ssum += ex;
    const float2 f = *reinterpret_cast<const float2*>(fs + (size_t)s*128 + lane*2);
    ax += ex*f.x; ay += ex*f.y;
  }
  float inv = (r1 > r0) ? 1.f/ssum : 0.f;
  float2 o;
  o.x = eluf(ax*inv + bias[lane*2]);
  o.y = eluf(ay*inv + bias[lane*2+1]);
  *reinterpret_cast<float2*>(&hOut[(size_t)d*128 + lane*2]) = o;
}

__global__ __launch_bounds__(256) void k_node3(
    const int* __restrict__ rowptr, const int* __restrict__ ecsr, const int* __restrict__ src,
    const float* __restrict__ el, const float* __restrict__ er, const float* __restrict__ f,
    const float* __restrict__ pr, const int* __restrict__ flag,
    void* __restrict__ out, int N){
  const float* bc = pr + 86784;
  int t = threadIdx.x;
  int wid = t >> 6, lane = t & 63;
  int d = blockIdx.x*4 + wid;
  if (d >= N) return;
  int r0 = rowptr[d], r1 = rowptr[d+1];
  const float4 erd = *reinterpret_cast<const float4*>(er + (size_t)d*4);
  float4 m = make_float4(-INFINITY,-INFINITY,-INFINITY,-INFINITY);
  for (int i = r0 + lane; i < r1; i += 64){
    int e = ecsr[i];
    int s = src[e];
    const float4 els = *reinterpret_cast<const float4*>(el + (size_t)s*4);
    m.x = fmaxf(m.x, lrelu(els.x + erd.x));
    m.y = fmaxf(m.y, lrelu(els.y + erd.y));
    m.z = fmaxf(m.z, lrelu(els.z + erd.z));
    m.w = fmaxf(m.w, lrelu(els.w + erd.w));
  }
  #pragma unroll
  for (int off=1; off<64; off<<=1){
    m.x = fmaxf(m.x, __shfl_xor(m.x, off));
    m.y = fmaxf(m.y, __shfl_xor(m.y, off));
    m.z = fmaxf(m.z, __shfl_xor(m.z, off));
    m.w = fmaxf(m.w, __shfl_xor(m.w, off));
  }
  int h = lane >> 4;
  float mh  = (h==0)?m.x:(h==1)?m.y:(h==2)?m.z:m.w;
  float erh = (h==0)?erd.x:(h==1)?erd.y:(h==2)?erd.z:erd.w;
  float ax=0.f, ay=0.f, ssum=0.f;
  for (int i = r0; i < r1; ++i){
    int e = ecsr[i];
    int s = src[e];
    float sc = lrelu(el[(size_t)s*4 + h] + erh);
    float ex = __expf(sc - mh);
    ssum += ex;
    const float2 ff = *reinterpret_cast<const float2*>(f + (size_t)s*128 + lane*2);
    ax += ex*ff.x; ay += ex*ff.y;
  }
  float inv = (r1 > r0) ? 1.f/ssum : 0.f;
  float ox = ax*inv + bc[lane*2];
  float oy = ay*inv + bc[lane*2+1];
  // mean over heads: sum lanes {l, l^16, l^32, l^48}
  ox += __shfl_xor(ox, 16); oy += __shfl_xor(oy, 16);
  ox += __shfl_xor(ox, 32); oy += __shfl_xor(oy, 32);
  ox *= 0.25f; oy *= 0.25f;
  // softmax over 32 logits held as pairs across each 16-lane group
  float mm = fmaxf(ox, oy);
  #pragma unroll
  for (int off=1; off<16; off<<=1) mm = fmaxf(mm, __shfl_xor(mm, off));
  float exx = __expf(ox - mm), exy = __expf(oy - mm);
  float ss = exx + exy;
  #pragma unroll
  for (int off=1; off<16; off<<=1) ss += __shfl_xor(ss, off);
  float rs = 1.f/ss;
  if (lane < 16){
    if (flag[0]){
      float2 o = make_float2(exx*rs, exy*rs);
      *reinterpret_cast<float2*>((float*)out + (size_t)d*32 + lane*2) = o;
    } else {
      u32 pck = (u32)f2bf(exx*rs) | ((u32)f2bf(exy*rs) << 16);
      ((u32*)out)[(size_t)d*16 + lane] = pck;
    }
  }
}

// ---------------- GEMM: out = X @ W (optionally two W's), all f32 ----------------
template<bool TWO>
__global__ __launch_bounds__(256) void k_gemm(
    const float* __restrict__ X, const float* __restrict__ Ws, const float* __restrict__ Wd,
    float* __restrict__ outS, float* __restrict__ outD, int N){
  __shared__ float xs[64*128];
  int t = threadIdx.x;
  int row0 = blockIdx.x * 64;
  #pragma unroll
  for (int i = 0; i < 8; ++i){
    int idx = t + i*256;            // float4 index, 0..2047
    int r = idx >> 5;
    int c4 = idx & 31;
    float4 v = make_float4(0.f,0.f,0.f,0.f);
    if (row0 + r < N) v = *reinterpret_cast<const float4*>(X + (size_t)(row0+r)*128 + c4*4);
    *reinterpret_cast<float4*>(&xs[r*128 + c4*4]) = v;
  }
  __syncthreads();
  int rg = t >> 5, jg = t & 31;
  float accS[8][4]; float accD[8][4];
  #pragma unroll
  for (int r=0;r<8;++r)
    #pragma unroll
    for (int c=0;c<4;++c){ accS[r][c]=0.f; accD[r][c]=0.f; }
  const float* xbase = &xs[(rg*8)*128];
  for (int k4 = 0; k4 < 32; ++k4){
    float4 xv[8];
    #pragma unroll
    for (int r=0;r<8;++r) xv[r] = *reinterpret_cast<const float4*>(xbase + r*128 + k4*4);
    #pragma unroll
    for (int kk=0;kk<4;++kk){
      int k = k4*4 + kk;
      float4 ws4 = *reinterpret_cast<const float4*>(Ws + k*128 + jg*4);
      #pragma unroll
      for (int r=0;r<8;++r){
        float xk = (kk==0)?xv[r].x:(kk==1)?xv[r].y:(kk==2)?xv[r].z:xv[r].w;
        accS[r][0] += xk*ws4.x; accS[r][1] += xk*ws4.y;
        accS[r][2] += xk*ws4.z; accS[r][3] += xk*ws4.w;
      }
      if (TWO){
        float4 wd4 = *reinterpret_cast<const float4*>(Wd + k*128 + jg*4);
        #pragma unroll
        for (int r=0;r<8;++r){
          float xk = (kk==0)?xv[r].x:(kk==1)?xv[r].y:(kk==2)?xv[r].z:xv[r].w;
          accD[r][0] += xk*wd4.x; accD[r][1] += xk*wd4.y;
          accD[r][2] += xk*wd4.z; accD[r][3] += xk*wd4.w;
        }
      }
    }
  }
  #pragma unroll
  for (int r=0;r<8;++r){
    int row = row0 + rg*8 + r;
    if (row < N){
      *reinterpret_cast<float4*>(outS + (size_t)row*128 + jg*4) =
          make_float4(accS[r][0],accS[r][1],accS[r][2],accS[r][3]);
      if (TWO){
        *reinterpret_cast<float4*>(outD + (size_t)row*128 + jg*4) =
            make_float4(accD[r][0],accD[r][1],accD[r][2],accD[r][3]);
      }
    }
  }
}

// ---------------- GATv2 edge scores (layer 2) ----------------
__global__ __launch_bounds__(256) void k_score(
    const float* __restrict__ fs, const float* __restrict__ fd, const float* __restrict__ pr,
    const int* __restrict__ src, const int* __restrict__ dst, float* __restrict__ score, int E){
  const float* a = pr + 69888;
  int g = blockIdx.x*256 + threadIdx.x;
  int e = g >> 2, h = g & 3;
  if (e >= E) return;
  int s = src[e], d = dst[e];
  const float4* fs4 = reinterpret_cast<const float4*>(fs + (size_t)s*128 + h*32);
  const float4* fd4 = reinterpret_cast<const float4*>(fd + (size_t)d*128 + h*32);
  const float4* a4 = reinterpret_cast<const float4*>(a + h*32);
  float acc = 0.f;
  #pragma unroll
  for (int q = 0; q < 8; ++q){
    float4 x = fs4[q], y = fd4[q];
    float4 au = a4[q];
    acc += au.x * lrelu(x.x + y.x);
    acc += au.y * lrelu(x.y + y.y);
    acc += au.z * lrelu(x.z + y.z);
    acc += au.w * lrelu(x.w + y.w);
  }
  score[(size_t)e*4 + h] = acc;
}

// ---------------- per-node el/er for GAT v1 ----------------
__global__ void k_el(const float* __restrict__ f, const float* __restrict__ pr,
                     float* __restrict__ el, float* __restrict__ er, int N){
  const float* al = pr + 86528;
  const float* ar = pr + 86656;
  int g = blockIdx.x*256 + threadIdx.x;
  if (g >= N*4) return;
  int n = g >> 2, h = g & 3;
  const float4* f4 = reinterpret_cast<const float4*>(f + (size_t)n*128 + h*32);
  const float4* al4 = reinterpret_cast<const float4*>(al + h*32);
  const float4* ar4 = reinterpret_cast<const float4*>(ar + h*32);
  float aL=0.f, aR=0.f;
  #pragma unroll
  for (int q=0;q<8;++q){
    float4 x = f4[q];
    float4 u = al4[q], v = ar4[q];
    aL += u.x*x.x + u.y*x.y + u.z*x.z + u.w*x.w;
    aR += v.x*x.x + v.y*x.y + v.z*x.z + v.w*x.w;
  }
  el[g] = aL; er[g] = aR;
}

extern "C" void kernel_launch(void* const* d_in, const int* in_sizes, int n_in,
                              void* d_out, int out_size, void* d_ws, size_t ws_size,
                              hipStream_t stream){
  const int* in_feat = (const int*)d_in[0];
  const int* src     = (const int*)d_in[1];
  const int* dstA    = (const int*)d_in[2];
  const int N = in_sizes[0];
  const int E = in_sizes[1];

  char* p = (char*)d_ws;
  auto alloc = [&](size_t bytes)->char*{
    char* r = p; p += (bytes + 255) & ~(size_t)255; return r;
  };
  float* big0   = (float*)alloc((size_t)N*128*4);   // fs2, then f3
  float* big1   = (float*)alloc((size_t)N*128*4);   // fd2, then h2
  float* big2   = (float*)alloc((size_t)N*128*4);   // h1, then score (E*4 floats <= N*128)
  int*   deg    = (int*)alloc((size_t)N*4);
  int*   rowptr = (int*)alloc((size_t)(N+1)*4);
  int*   cursor = (int*)alloc((size_t)N*4);
  int*   ecsr   = (int*)alloc((size_t)E*4);
  float* Ts     = (float*)alloc(4096*4);
  float* Td     = (float*)alloc(4096*4);
  float* S1     = (float*)alloc(4096*4);
  float* el     = (float*)alloc((size_t)N*4*4);
  float* er     = (float*)alloc((size_t)N*4*4);
  float* parena = (float*)alloc(86912*4);
  int*   flag   = (int*)alloc(256);

  // dtype probe + param conversion
  k_probe<<<1,64,0,stream>>>((const u16*)d_in[4], flag);
  Params13 P;
  const int sz[13]  = {4096,16384,16384,128,128,16384,16384,128,128,16384,128,128,128};
  int off = 0;
  for (int t = 0; t < 13; ++t){
    P.src[t] = d_in[3 + t];
    P.n[t] = sz[t];
    P.off[t] = off;
    off += sz[t];
  }
  k_cvt<<<dim3(64,13),256,0,stream>>>(P, flag, parena);

  hipMemsetAsync(deg, 0, (size_t)N*4, stream);
  int gE = (E + 255)/256;
  k_deg<<<gE,256,0,stream>>>(dstA, deg, E);
  k_scan<<<1,64,0,stream>>>(deg, rowptr, cursor, N);
  k_scatter<<<gE,256,0,stream>>>(dstA, cursor, ecsr, E);

  k_tinyA<<<16,256,0,stream>>>(parena, Ts, Td);
  k_tinyB<<<16,256,0,stream>>>(Ts, Td, parena, S1);

  int gN4 = (N + 3)/4;
  float* h1 = big2;
  k_node1<<<gN4,256,0,stream>>>(rowptr, ecsr, src, in_feat, Ts, S1, parena, h1, N);

  int gG = (N + 63)/64;
  float* fs2 = big0; float* fd2 = big1;
  k_gemm<true><<<gG,256,0,stream>>>(h1, parena + 37120, parena + 53504, fs2, fd2, N);

  float* score = big2;   // h1 dead
  int gS = (int)(((size_t)E*4 + 255)/256);
  k_score<<<gS,256,0,stream>>>(fs2, fd2, parena, src, dstA, score, E);

  float* h2 = big1;      // fd2 dead
  { // node2 with b2 bias
    k_node2<<<gN4,256,0,stream>>>(rowptr, ecsr, src, score, fs2, parena + 70016, h2, N);
  }

  float* f3 = big0;      // fs2 dead
  k_gemm<false><<<gG,256,0,stream>>>(h2, parena + 70144, nullptr, f3, nullptr, N);

  int gEl = (int)(((size_t)N*4 + 255)/256);
  k_el<<<gEl,256,0,stream>>>(f3, parena, el, er, N);

  k_node3<<<gN4,256,0,stream>>>(rowptr, ecsr, src, el, er, f3, parena, flag, d_out, N);
}

// Round 3
// 503.496 us; speedup vs baseline: 1.8377x; 1.8377x over previous
//
#include <hip/hip_runtime.h>
#include <hip/hip_bf16.h>

typedef unsigned short u16;
typedef unsigned int u32;

#define NEG_SLOPE 0.2f

__device__ __forceinline__ float bf2f(u16 u){
  union { u32 i; float f; } c; c.i = ((u32)u) << 16; return c.f;
}
__device__ __forceinline__ u16 f2bf(float f){
  __hip_bfloat16 h = __float2bfloat16(f);
  u16 u; __builtin_memcpy(&u, &h, 2); return u;
}
__device__ __forceinline__ float lrelu(float x){
  return fmaxf(x, 0.f) + NEG_SLOPE * fminf(x, 0.f);
}
__device__ __forceinline__ float eluf(float x){
  return x > 0.f ? x : (__expf(x) - 1.f);
}

// ---------------- dtype probe ----------------
__global__ void k_probe(const u16* __restrict__ w, int* __restrict__ flag){
  int t = threadIdx.x;
  int hit = 0;
  for (int i = t; i < 4096; i += 64){
    u16 v = w[i];
    int e = (v >> 7) & 0xFF;
    if (e >= 200) hit = 1;
  }
  unsigned long long b = __ballot(hit);
  if (t == 0) flag[0] = b ? 1 : 0;   // 1 => float32 data
}

// ---------------- param conversion to f32 arena ----------------
struct Params13 {
  const void* src[13];
  int off[13];
  int n[13];
};

__global__ void k_cvt(Params13 P, const int* __restrict__ flag, float* __restrict__ dst){
  int t = blockIdx.y;
  int i = blockIdx.x*256 + threadIdx.x;
  if (i >= P.n[t]) return;
  int f = flag[0];
  float v = f ? ((const float*)P.src[t])[i] : bf2f(((const u16*)P.src[t])[i]);
  dst[P.off[t] + i] = v;
}

// ---------------- CSR build ----------------
__global__ void k_deg(const int* __restrict__ dst, int* __restrict__ deg, int E){
  int i = blockIdx.x*256 + threadIdx.x;
  if (i < E) atomicAdd(&deg[dst[i]], 1);
}

// block sums of deg (256 per block)
__global__ __launch_bounds__(256) void k_bsum(const int* __restrict__ deg,
                                              int* __restrict__ bsum, int N){
  __shared__ int ws[4];
  int t = threadIdx.x;
  int i = blockIdx.x*256 + t;
  int v = (i < N) ? deg[i] : 0;
  #pragma unroll
  for (int off=32; off>=1; off>>=1) v += __shfl_down(v, off);
  if ((t & 63) == 0) ws[t>>6] = v;
  __syncthreads();
  if (t == 0) bsum[blockIdx.x] = ws[0]+ws[1]+ws[2]+ws[3];
}

// single-wave exclusive scan of nb block sums -> boff; writes rowptr[N]=total
__global__ void k_scanb(const int* __restrict__ bsum, int* __restrict__ boff,
                        int* __restrict__ rowptr, int nb, int N){
  int l = threadIdx.x;
  int carry = 0;
  int nChunk = (nb + 63) >> 6;
  for (int c = 0; c < nChunk; ++c){
    int idx = (c << 6) + l;
    int v = (idx < nb) ? bsum[idx] : 0;
    int x = v;
    #pragma unroll
    for (int off=1; off<64; off<<=1){
      int y = __shfl_up(x, off);
      if (l >= off) x += y;
    }
    if (idx < nb) boff[idx] = carry + x - v;
    carry += __shfl(x, 63);
  }
  if (l == 0) rowptr[N] = carry;
}

// per-block exclusive scan + boff -> rowptr, cursor
__global__ __launch_bounds__(256) void k_scan2(const int* __restrict__ deg,
                                               const int* __restrict__ boff,
                                               int* __restrict__ rowptr,
                                               int* __restrict__ cursor, int N){
  __shared__ int ws[4];
  int t = threadIdx.x;
  int i = blockIdx.x*256 + t;
  int lane = t & 63, wid = t >> 6;
  int v = (i < N) ? deg[i] : 0;
  int x = v;
  #pragma unroll
  for (int off=1; off<64; off<<=1){
    int y = __shfl_up(x, off);
    if (lane >= off) x += y;
  }
  if (lane == 63) ws[wid] = x;
  __syncthreads();
  int woff = 0;
  #pragma unroll
  for (int w=0; w<4; ++w) woff += (w < wid) ? ws[w] : 0;
  int excl = boff[blockIdx.x] + woff + x - v;
  if (i < N){ rowptr[i] = excl; cursor[i] = excl; }
}

// scatter: store src id and src node-type per CSR slot
__global__ void k_scatter(const int* __restrict__ src, const int* __restrict__ dst,
                          const int* __restrict__ vf, int* __restrict__ cursor,
                          int* __restrict__ esrc, int* __restrict__ evf, int E){
  int i = blockIdx.x*256 + threadIdx.x;
  if (i < E){
    int d = dst[i];
    int s = src[i];
    int pos = atomicAdd(&cursor[d], 1);
    esrc[pos] = s;
    evf[pos] = vf[s];
  }
}

// ---------------- layer-1 tiny tables ----------------
__global__ void k_tinyA(const float* __restrict__ pr,
                        float* __restrict__ Ts, float* __restrict__ Td){
  const float* emb = pr + 0;
  const float* W1s = pr + 4096;
  const float* W1d = pr + 20480;
  int g = blockIdx.x*256 + threadIdx.x;   // 0..4095
  int v = g >> 7, j = g & 127;
  float as = 0.f, ad = 0.f;
  for (int k = 0; k < 128; ++k){
    float e = emb[v*128 + k];
    as += e * W1s[k*128 + j];
    ad += e * W1d[k*128 + j];
  }
  Ts[g] = as; Td[g] = ad;
}

__global__ void k_tinyB(const float* __restrict__ Ts, const float* __restrict__ Td,
                        const float* __restrict__ pr, float* __restrict__ S1){
  const float* a1 = pr + 36864;
  int g = blockIdx.x*256 + threadIdx.x;   // vs*128 + vd*4 + h
  int vs = g >> 7, vd = (g >> 2) & 31, h = g & 3;
  float acc = 0.f;
  for (int dd = 0; dd < 32; ++dd){
    float x = Ts[vs*128 + h*32 + dd] + Td[vd*128 + h*32 + dd];
    acc += a1[h*32 + dd] * lrelu(x);
  }
  S1[g] = acc;
}

// ---------------- node1: 64 dst nodes per block, tables in LDS ----------------
__global__ __launch_bounds__(256) void k_node1(
    const int* __restrict__ rowptr, const int* __restrict__ evf,
    const int* __restrict__ vf, const float* __restrict__ Ts, const float* __restrict__ S1,
    const float* __restrict__ pr, float* __restrict__ hOut, int N){
  const float* b1 = pr + 36992;
  __shared__ float TsL[4096];
  __shared__ float S1L[4096];
  int t = threadIdx.x;
  for (int i = t; i < 4096; i += 256){ TsL[i] = Ts[i]; S1L[i] = S1[i]; }
  __syncthreads();
  int wid = t >> 6, lane = t & 63;
  int h = lane >> 4;
  float bx = b1[lane*2], by = b1[lane*2+1];
  int base = blockIdx.x * 64;
  for (int dd = wid; dd < 64; dd += 4){
    int d = base + dd;
    if (d >= N) break;
    int r0 = rowptr[d], r1 = rowptr[d+1];
    int vfd = vf[d];
    float4 m = make_float4(-INFINITY,-INFINITY,-INFINITY,-INFINITY);
    for (int i = r0 + lane; i < r1; i += 64){
      int vs = evf[i];
      const float4 sc = *reinterpret_cast<const float4*>(&S1L[(vs*32 + vfd)*4]);
      m.x = fmaxf(m.x, sc.x); m.y = fmaxf(m.y, sc.y);
      m.z = fmaxf(m.z, sc.z); m.w = fmaxf(m.w, sc.w);
    }
    #pragma unroll
    for (int off=1; off<64; off<<=1){
      m.x = fmaxf(m.x, __shfl_xor(m.x, off));
      m.y = fmaxf(m.y, __shfl_xor(m.y, off));
      m.z = fmaxf(m.z, __shfl_xor(m.z, off));
      m.w = fmaxf(m.w, __shfl_xor(m.w, off));
    }
    float mh = (h==0)?m.x:(h==1)?m.y:(h==2)?m.z:m.w;
    float ax = 0.f, ay = 0.f, ssum = 0.f;
    for (int i = r0; i < r1; ++i){
      int vs = evf[i];
      float sc = S1L[(vs*32 + vfd)*4 + h];
      float ex = __expf(sc - mh);
      ssum += ex;
      const float2 f = *reinterpret_cast<const float2*>(&TsL[vs*128 + lane*2]);
      ax += ex * f.x; ay += ex * f.y;
    }
    float inv = (r1 > r0) ? 1.f/ssum : 0.f;
    float2 o;
    o.x = eluf(ax*inv + bx);
    o.y = eluf(ay*inv + by);
    *reinterpret_cast<float2*>(&hOut[(size_t)d*128 + lane*2]) = o;
  }
}

// ---------------- node2 fused: score + online softmax + aggregate ----------------
__global__ __launch_bounds__(256) void k_node2f(
    const int* __restrict__ rowptr, const int* __restrict__ esrc,
    const float* __restrict__ fs, const float* __restrict__ fd,
    const float* __restrict__ pr, float* __restrict__ hOut, int N){
  const float* a2 = pr + 69888;
  const float* b2 = pr + 70016;
  int t = threadIdx.x;
  int wid = t >> 6, lane = t & 63;
  int d = blockIdx.x*4 + wid;
  if (d >= N) return;
  int r0 = rowptr[d], r1 = rowptr[d+1];
  float ax_ = a2[lane*2], ay_ = a2[lane*2+1];
  const float2 fdv = *reinterpret_cast<const float2*>(fd + (size_t)d*128 + lane*2);
  float m = -INFINITY, ssum = 0.f, accx = 0.f, accy = 0.f;
  for (int i = r0; i < r1; ++i){
    int s = esrc[i];
    const float2 fsv = *reinterpret_cast<const float2*>(fs + (size_t)s*128 + lane*2);
    float p = ax_*lrelu(fsv.x + fdv.x) + ay_*lrelu(fsv.y + fdv.y);
    p += __shfl_xor(p, 1); p += __shfl_xor(p, 2);
    p += __shfl_xor(p, 4); p += __shfl_xor(p, 8);
    float mn = fmaxf(m, p);
    float cor = __expf(m - mn);
    float w = __expf(p - mn);
    ssum = ssum*cor + w;
    accx = accx*cor + w*fsv.x;
    accy = accy*cor + w*fsv.y;
    m = mn;
  }
  float inv = (r1 > r0) ? 1.f/ssum : 0.f;
  float2 o;
  o.x = eluf(accx*inv + b2[lane*2]);
  o.y = eluf(accy*inv + b2[lane*2+1]);
  *reinterpret_cast<float2*>(&hOut[(size_t)d*128 + lane*2]) = o;
}

// ---------------- node3 fused: GAT v1 + head mean + final softmax ----------------
__global__ __launch_bounds__(256) void k_node3f(
    const int* __restrict__ rowptr, const int* __restrict__ esrc,
    const float* __restrict__ el, const float* __restrict__ er, const float* __restrict__ f,
    const float* __restrict__ pr, const int* __restrict__ flag,
    void* __restrict__ out, int N){
  const float* bc = pr + 86784;
  int t = threadIdx.x;
  int wid = t >> 6, lane = t & 63;
  int d = blockIdx.x*4 + wid;
  if (d >= N) return;
  int r0 = rowptr[d], r1 = rowptr[d+1];
  int h = lane >> 4;
  float erh = er[(size_t)d*4 + h];
  float m = -INFINITY, ssum = 0.f, accx = 0.f, accy = 0.f;
  for (int i = r0; i < r1; ++i){
    int s = esrc[i];
    float sc = lrelu(el[(size_t)s*4 + h] + erh);
    const float2 fv = *reinterpret_cast<const float2*>(f + (size_t)s*128 + lane*2);
    float mn = fmaxf(m, sc);
    float cor = __expf(m - mn);
    float w = __expf(sc - mn);
    ssum = ssum*cor + w;
    accx = accx*cor + w*fv.x;
    accy = accy*cor + w*fv.y;
    m = mn;
  }
  float inv = (r1 > r0) ? 1.f/ssum : 0.f;
  float ox = accx*inv + bc[lane*2];
  float oy = accy*inv + bc[lane*2+1];
  // mean over heads: sum lanes {l, l^16, l^32, l^48}
  ox += __shfl_xor(ox, 16); oy += __shfl_xor(oy, 16);
  ox += __shfl_xor(ox, 32); oy += __shfl_xor(oy, 32);
  ox *= 0.25f; oy *= 0.25f;
  // softmax over 32 logits held as pairs across each 16-lane group
  float mm = fmaxf(ox, oy);
  #pragma unroll
  for (int off=1; off<16; off<<=1) mm = fmaxf(mm, __shfl_xor(mm, off));
  float exx = __expf(ox - mm), exy = __expf(oy - mm);
  float ss = exx + exy;
  #pragma unroll
  for (int off=1; off<16; off<<=1) ss += __shfl_xor(ss, off);
  float rs = 1.f/ss;
  if (lane < 16){
    if (flag[0]){
      float2 o = make_float2(exx*rs, exy*rs);
      *reinterpret_cast<float2*>((float*)out + (size_t)d*32 + lane*2) = o;
    } else {
      u32 pck = (u32)f2bf(exx*rs) | ((u32)f2bf(exy*rs) << 16);
      ((u32*)out)[(size_t)d*16 + lane] = pck;
    }
  }
}

// ---------------- GEMM: out = X @ W (optionally two W's), all f32 ----------------
template<bool TWO>
__global__ __launch_bounds__(256) void k_gemm(
    const float* __restrict__ X, const float* __restrict__ Ws, const float* __restrict__ Wd,
    float* __restrict__ outS, float* __restrict__ outD, int N){
  __shared__ float xs[64*128];
  int t = threadIdx.x;
  int row0 = blockIdx.x * 64;
  #pragma unroll
  for (int i = 0; i < 8; ++i){
    int idx = t + i*256;            // float4 index, 0..2047
    int r = idx >> 5;
    int c4 = idx & 31;
    float4 v = make_float4(0.f,0.f,0.f,0.f);
    if (row0 + r < N) v = *reinterpret_cast<const float4*>(X + (size_t)(row0+r)*128 + c4*4);
    *reinterpret_cast<float4*>(&xs[r*128 + c4*4]) = v;
  }
  __syncthreads();
  int rg = t >> 5, jg = t & 31;
  float accS[8][4]; float accD[8][4];
  #pragma unroll
  for (int r=0;r<8;++r)
    #pragma unroll
    for (int c=0;c<4;++c){ accS[r][c]=0.f; accD[r][c]=0.f; }
  const float* xbase = &xs[(rg*8)*128];
  for (int k4 = 0; k4 < 32; ++k4){
    float4 xv[8];
    #pragma unroll
    for (int r=0;r<8;++r) xv[r] = *reinterpret_cast<const float4*>(xbase + r*128 + k4*4);
    #pragma unroll
    for (int kk=0;kk<4;++kk){
      int k = k4*4 + kk;
      float4 ws4 = *reinterpret_cast<const float4*>(Ws + k*128 + jg*4);
      #pragma unroll
      for (int r=0;r<8;++r){
        float xk = (kk==0)?xv[r].x:(kk==1)?xv[r].y:(kk==2)?xv[r].z:xv[r].w;
        accS[r][0] += xk*ws4.x; accS[r][1] += xk*ws4.y;
        accS[r][2] += xk*ws4.z; accS[r][3] += xk*ws4.w;
      }
      if (TWO){
        float4 wd4 = *reinterpret_cast<const float4*>(Wd + k*128 + jg*4);
        #pragma unroll
        for (int r=0;r<8;++r){
          float xk = (kk==0)?xv[r].x:(kk==1)?xv[r].y:(kk==2)?xv[r].z:xv[r].w;
          accD[r][0] += xk*wd4.x; accD[r][1] += xk*wd4.y;
          accD[r][2] += xk*wd4.z; accD[r][3] += xk*wd4.w;
        }
      }
    }
  }
  #pragma unroll
  for (int r=0;r<8;++r){
    int row = row0 + rg*8 + r;
    if (row < N){
      *reinterpret_cast<float4*>(outS + (size_t)row*128 + jg*4) =
          make_float4(accS[r][0],accS[r][1],accS[r][2],accS[r][3]);
      if (TWO){
        *reinterpret_cast<float4*>(outD + (size_t)row*128 + jg*4) =
            make_float4(accD[r][0],accD[r][1],accD[r][2],accD[r][3]);
      }
    }
  }
}

// ---------------- per-node el/er for GAT v1 ----------------
__global__ void k_el(const float* __restrict__ f, const float* __restrict__ pr,
                     float* __restrict__ el, float* __restrict__ er, int N){
  const float* al = pr + 86528;
  const float* ar = pr + 86656;
  int g = blockIdx.x*256 + threadIdx.x;
  if (g >= N*4) return;
  int n = g >> 2, h = g & 3;
  const float4* f4 = reinterpret_cast<const float4*>(f + (size_t)n*128 + h*32);
  const float4* al4 = reinterpret_cast<const float4*>(al + h*32);
  const float4* ar4 = reinterpret_cast<const float4*>(ar + h*32);
  float aL=0.f, aR=0.f;
  #pragma unroll
  for (int q=0;q<8;++q){
    float4 x = f4[q];
    float4 u = al4[q], v = ar4[q];
    aL += u.x*x.x + u.y*x.y + u.z*x.z + u.w*x.w;
    aR += v.x*x.x + v.y*x.y + v.z*x.z + v.w*x.w;
  }
  el[g] = aL; er[g] = aR;
}

extern "C" void kernel_launch(void* const* d_in, const int* in_sizes, int n_in,
                              void* d_out, int out_size, void* d_ws, size_t ws_size,
                              hipStream_t stream){
  const int* in_feat = (const int*)d_in[0];
  const int* src     = (const int*)d_in[1];
  const int* dstA    = (const int*)d_in[2];
  const int N = in_sizes[0];
  const int E = in_sizes[1];

  char* p = (char*)d_ws;
  auto alloc = [&](size_t bytes)->char*{
    char* r = p; p += (bytes + 255) & ~(size_t)255; return r;
  };
  float* big0   = (float*)alloc((size_t)N*128*4);   // fs2, then f3
  float* big1   = (float*)alloc((size_t)N*128*4);   // fd2, then h2
  float* big2   = (float*)alloc((size_t)N*128*4);   // h1
  int*   deg    = (int*)alloc((size_t)N*4);
  int*   rowptr = (int*)alloc((size_t)(N+1)*4);
  int*   cursor = (int*)alloc((size_t)N*4);
  int*   bsum   = (int*)alloc(1024*4);
  int*   boff   = (int*)alloc(1024*4);
  int*   esrc   = (int*)alloc((size_t)E*4);
  int*   evf    = (int*)alloc((size_t)E*4);
  float* Ts     = (float*)alloc(4096*4);
  float* Td     = (float*)alloc(4096*4);
  float* S1     = (float*)alloc(4096*4);
  float* el     = (float*)alloc((size_t)N*4*4);
  float* er     = (float*)alloc((size_t)N*4*4);
  float* parena = (float*)alloc(86912*4);
  int*   flag   = (int*)alloc(256);

  // dtype probe + param conversion
  k_probe<<<1,64,0,stream>>>((const u16*)d_in[4], flag);
  Params13 P;
  const int sz[13]  = {4096,16384,16384,128,128,16384,16384,128,128,16384,128,128,128};
  int off = 0;
  for (int t = 0; t < 13; ++t){
    P.src[t] = d_in[3 + t];
    P.n[t] = sz[t];
    P.off[t] = off;
    off += sz[t];
  }
  k_cvt<<<dim3(64,13),256,0,stream>>>(P, flag, parena);

  hipMemsetAsync(deg, 0, (size_t)N*4, stream);
  int gE = (E + 255)/256;
  int nb = (N + 255)/256;
  k_deg<<<gE,256,0,stream>>>(dstA, deg, E);
  k_bsum<<<nb,256,0,stream>>>(deg, bsum, N);
  k_scanb<<<1,64,0,stream>>>(bsum, boff, rowptr, nb, N);
  k_scan2<<<nb,256,0,stream>>>(deg, boff, rowptr, cursor, N);
  k_scatter<<<gE,256,0,stream>>>(src, dstA, in_feat, cursor, esrc, evf, E);

  k_tinyA<<<16,256,0,stream>>>(parena, Ts, Td);
  k_tinyB<<<16,256,0,stream>>>(Ts, Td, parena, S1);

  float* h1 = big2;
  int gN64 = (N + 63)/64;
  k_node1<<<gN64,256,0,stream>>>(rowptr, evf, in_feat, Ts, S1, parena, h1, N);

  int gG = (N + 63)/64;
  float* fs2 = big0; float* fd2 = big1;
  k_gemm<true><<<gG,256,0,stream>>>(h1, parena + 37120, parena + 53504, fs2, fd2, N);

  int gN4 = (N + 3)/4;
  float* h2 = big2;      // h1 consumed by gemm; reuse
  k_node2f<<<gN4,256,0,stream>>>(rowptr, esrc, fs2, fd2, parena, h2, N);

  float* f3 = big0;      // fs2 dead after node2f
  k_gemm<false><<<gG,256,0,stream>>>(h2, parena + 70144, nullptr, f3, nullptr, N);

  int gEl = (int)(((size_t)N*4 + 255)/256);
  k_el<<<gEl,256,0,stream>>>(f3, parena, el, er, N);

  k_node3f<<<gN4,256,0,stream>>>(rowptr, esrc, el, er, f3, parena, flag, d_out, N);
}

// Round 4
// 411.071 us; speedup vs baseline: 2.2509x; 1.2248x over previous
//
#include <hip/hip_runtime.h>
#include <hip/hip_bf16.h>

typedef unsigned short u16;
typedef unsigned int u32;

#define NEG_SLOPE 0.2f

__device__ __forceinline__ float bf2f(u16 u){
  union { u32 i; float f; } c; c.i = ((u32)u) << 16; return c.f;
}
__device__ __forceinline__ u16 f2bf(float f){
  __hip_bfloat16 h = __float2bfloat16(f);
  u16 u; __builtin_memcpy(&u, &h, 2); return u;
}
__device__ __forceinline__ float lrelu(float x){
  return fmaxf(x, 0.f) + NEG_SLOPE * fminf(x, 0.f);
}
__device__ __forceinline__ float eluf(float x){
  return x > 0.f ? x : (__expf(x) - 1.f);
}

// ---------------- dtype probe ----------------
__global__ void k_probe(const u16* __restrict__ w, int* __restrict__ flag){
  int t = threadIdx.x;
  int hit = 0;
  for (int i = t; i < 4096; i += 64){
    u16 v = w[i];
    int e = (v >> 7) & 0xFF;
    if (e >= 200) hit = 1;
  }
  unsigned long long b = __ballot(hit);
  if (t == 0) flag[0] = b ? 1 : 0;   // 1 => float32 data
}

// ---------------- param conversion to f32 arena ----------------
struct Params13 {
  const void* src[13];
  int off[13];
  int n[13];
};

__global__ void k_cvt(Params13 P, const int* __restrict__ flag, float* __restrict__ dst){
  int t = blockIdx.y;
  int i = blockIdx.x*256 + threadIdx.x;
  if (i >= P.n[t]) return;
  int f = flag[0];
  float v = f ? ((const float*)P.src[t])[i] : bf2f(((const u16*)P.src[t])[i]);
  dst[P.off[t] + i] = v;
}

// ---------------- CSR build ----------------
__global__ void k_deg(const int* __restrict__ dst, int* __restrict__ deg, int E){
  int i = blockIdx.x*256 + threadIdx.x;
  if (i < E) atomicAdd(&deg[dst[i]], 1);
}

__global__ __launch_bounds__(256) void k_bsum(const int* __restrict__ deg,
                                              int* __restrict__ bsum, int N){
  __shared__ int ws[4];
  int t = threadIdx.x;
  int i = blockIdx.x*256 + t;
  int v = (i < N) ? deg[i] : 0;
  #pragma unroll
  for (int off=32; off>=1; off>>=1) v += __shfl_down(v, off);
  if ((t & 63) == 0) ws[t>>6] = v;
  __syncthreads();
  if (t == 0) bsum[blockIdx.x] = ws[0]+ws[1]+ws[2]+ws[3];
}

__global__ void k_scanb(const int* __restrict__ bsum, int* __restrict__ boff,
                        int* __restrict__ rowptr, int nb, int N){
  int l = threadIdx.x;
  int carry = 0;
  int nChunk = (nb + 63) >> 6;
  for (int c = 0; c < nChunk; ++c){
    int idx = (c << 6) + l;
    int v = (idx < nb) ? bsum[idx] : 0;
    int x = v;
    #pragma unroll
    for (int off=1; off<64; off<<=1){
      int y = __shfl_up(x, off);
      if (l >= off) x += y;
    }
    if (idx < nb) boff[idx] = carry + x - v;
    carry += __shfl(x, 63);
  }
  if (l == 0) rowptr[N] = carry;
}

__global__ __launch_bounds__(256) void k_scan2(const int* __restrict__ deg,
                                               const int* __restrict__ boff,
                                               int* __restrict__ rowptr,
                                               int* __restrict__ cursor, int N){
  __shared__ int ws[4];
  int t = threadIdx.x;
  int i = blockIdx.x*256 + t;
  int lane = t & 63, wid = t >> 6;
  int v = (i < N) ? deg[i] : 0;
  int x = v;
  #pragma unroll
  for (int off=1; off<64; off<<=1){
    int y = __shfl_up(x, off);
    if (lane >= off) x += y;
  }
  if (lane == 63) ws[wid] = x;
  __syncthreads();
  int woff = 0;
  #pragma unroll
  for (int w=0; w<4; ++w) woff += (w < wid) ? ws[w] : 0;
  int excl = boff[blockIdx.x] + woff + x - v;
  if (i < N){ rowptr[i] = excl; cursor[i] = excl; }
}

__global__ void k_scatter(const int* __restrict__ src, const int* __restrict__ dst,
                          const int* __restrict__ vf, int* __restrict__ cursor,
                          int* __restrict__ esrc, int* __restrict__ evf, int E){
  int i = blockIdx.x*256 + threadIdx.x;
  if (i < E){
    int d = dst[i];
    int s = src[i];
    int pos = atomicAdd(&cursor[d], 1);
    esrc[pos] = s;
    evf[pos] = vf[s];
  }
}

// ---------------- layer-1 tiny tables ----------------
__global__ void k_tinyA(const float* __restrict__ pr,
                        float* __restrict__ Ts, float* __restrict__ Td){
  const float* emb = pr + 0;
  const float* W1s = pr + 4096;
  const float* W1d = pr + 20480;
  int g = blockIdx.x*256 + threadIdx.x;   // 0..4095
  int v = g >> 7, j = g & 127;
  float as = 0.f, ad = 0.f;
  for (int k = 0; k < 128; ++k){
    float e = emb[v*128 + k];
    as += e * W1s[k*128 + j];
    ad += e * W1d[k*128 + j];
  }
  Ts[g] = as; Td[g] = ad;
}

__global__ void k_tinyB(const float* __restrict__ Ts, const float* __restrict__ Td,
                        const float* __restrict__ pr, float* __restrict__ S1){
  const float* a1 = pr + 36864;
  int g = blockIdx.x*256 + threadIdx.x;   // vs*128 + vd*4 + h
  int vs = g >> 7, vd = (g >> 2) & 31, h = g & 3;
  float acc = 0.f;
  for (int dd = 0; dd < 32; ++dd){
    float x = Ts[vs*128 + h*32 + dd] + Td[vd*128 + h*32 + dd];
    acc += a1[h*32 + dd] * lrelu(x);
  }
  S1[g] = acc;
}

// ---------------- node1: 64 dst nodes per block, tables in LDS ----------------
__global__ __launch_bounds__(256) void k_node1(
    const int* __restrict__ rowptr, const int* __restrict__ evf,
    const int* __restrict__ vf, const float* __restrict__ Ts, const float* __restrict__ S1,
    const float* __restrict__ pr, float* __restrict__ hOut, int N){
  const float* b1 = pr + 36992;
  __shared__ float TsL[4096];
  __shared__ float S1L[4096];
  int t = threadIdx.x;
  for (int i = t; i < 4096; i += 256){ TsL[i] = Ts[i]; S1L[i] = S1[i]; }
  __syncthreads();
  int wid = t >> 6, lane = t & 63;
  int h = lane >> 4;
  float bx = b1[lane*2], by = b1[lane*2+1];
  int base = blockIdx.x * 64;
  for (int dd = wid; dd < 64; dd += 4){
    int d = base + dd;
    if (d >= N) break;
    int r0 = rowptr[d], r1 = rowptr[d+1];
    int vfd = vf[d];
    float4 m = make_float4(-INFINITY,-INFINITY,-INFINITY,-INFINITY);
    for (int i = r0 + lane; i < r1; i += 64){
      int vs = evf[i];
      const float4 sc = *reinterpret_cast<const float4*>(&S1L[(vs*32 + vfd)*4]);
      m.x = fmaxf(m.x, sc.x); m.y = fmaxf(m.y, sc.y);
      m.z = fmaxf(m.z, sc.z); m.w = fmaxf(m.w, sc.w);
    }
    #pragma unroll
    for (int off=1; off<64; off<<=1){
      m.x = fmaxf(m.x, __shfl_xor(m.x, off));
      m.y = fmaxf(m.y, __shfl_xor(m.y, off));
      m.z = fmaxf(m.z, __shfl_xor(m.z, off));
      m.w = fmaxf(m.w, __shfl_xor(m.w, off));
    }
    float mh = (h==0)?m.x:(h==1)?m.y:(h==2)?m.z:m.w;
    float ax = 0.f, ay = 0.f, ssum = 0.f;
    for (int i = r0; i < r1; ++i){
      int vs = evf[i];
      float sc = S1L[(vs*32 + vfd)*4 + h];
      float ex = __expf(sc - mh);
      ssum += ex;
      const float2 f = *reinterpret_cast<const float2*>(&TsL[vs*128 + lane*2]);
      ax += ex * f.x; ay += ex * f.y;
    }
    float inv = (r1 > r0) ? 1.f/ssum : 0.f;
    float2 o;
    o.x = eluf(ax*inv + bx);
    o.y = eluf(ay*inv + by);
    *reinterpret_cast<float2*>(&hOut[(size_t)d*128 + lane*2]) = o;
  }
}

// ---------------- node2 fused: 4-edge x 16-lane online softmax ----------------
__global__ __launch_bounds__(256) void k_node2f(
    const int* __restrict__ rowptr, const int* __restrict__ esrc,
    const float* __restrict__ fs, const float* __restrict__ fd,
    const float* __restrict__ pr, float* __restrict__ hOut, int N){
  const float* a2 = pr + 69888;
  const float* b2 = pr + 70016;
  int t = threadIdx.x;
  int wid = t >> 6, lane = t & 63;
  int q = lane & 15, g = lane >> 4;   // lane q holds dims q*8..q*8+7; group g = edge stream
  int d = blockIdx.x*4 + wid;
  if (d >= N) return;
  int r0 = rowptr[d], r1 = rowptr[d+1];
  const float4 a2lo = *reinterpret_cast<const float4*>(a2 + q*8);
  const float4 a2hi = *reinterpret_cast<const float4*>(a2 + q*8 + 4);
  const float4 fdlo = *reinterpret_cast<const float4*>(fd + (size_t)d*128 + q*8);
  const float4 fdhi = *reinterpret_cast<const float4*>(fd + (size_t)d*128 + q*8 + 4);
  float m = -INFINITY, ssum = 0.f;
  float acc[8] = {0.f,0.f,0.f,0.f,0.f,0.f,0.f,0.f};
  for (int i = r0 + g; i < r1; i += 4){
    int s = esrc[i];
    const float4 f0 = *reinterpret_cast<const float4*>(fs + (size_t)s*128 + q*8);
    const float4 f1 = *reinterpret_cast<const float4*>(fs + (size_t)s*128 + q*8 + 4);
    float p = a2lo.x*lrelu(f0.x+fdlo.x) + a2lo.y*lrelu(f0.y+fdlo.y)
            + a2lo.z*lrelu(f0.z+fdlo.z) + a2lo.w*lrelu(f0.w+fdlo.w)
            + a2hi.x*lrelu(f1.x+fdhi.x) + a2hi.y*lrelu(f1.y+fdhi.y)
            + a2hi.z*lrelu(f1.z+fdhi.z) + a2hi.w*lrelu(f1.w+fdhi.w);
    p += __shfl_xor(p, 1); p += __shfl_xor(p, 2);   // head = 4-lane slice
    float mn = fmaxf(m, p);
    float cor = __expf(m - mn);
    float w = __expf(p - mn);
    ssum = ssum*cor + w;
    acc[0]=acc[0]*cor + w*f0.x; acc[1]=acc[1]*cor + w*f0.y;
    acc[2]=acc[2]*cor + w*f0.z; acc[3]=acc[3]*cor + w*f0.w;
    acc[4]=acc[4]*cor + w*f1.x; acc[5]=acc[5]*cor + w*f1.y;
    acc[6]=acc[6]*cor + w*f1.z; acc[7]=acc[7]*cor + w*f1.w;
    m = mn;
  }
  // merge the 4 groups' online states
  #pragma unroll
  for (int off = 16; off <= 32; off <<= 1){
    float mo  = __shfl_xor(m, off);
    float sso = __shfl_xor(ssum, off);
    float ao[8];
    #pragma unroll
    for (int k=0;k<8;++k) ao[k] = __shfl_xor(acc[k], off);
    float mn = fmaxf(m, mo);
    float c1 = (m  > -1e30f) ? __expf(m  - mn) : 0.f;
    float c2 = (mo > -1e30f) ? __expf(mo - mn) : 0.f;
    ssum = ssum*c1 + sso*c2;
    #pragma unroll
    for (int k=0;k<8;++k) acc[k] = acc[k]*c1 + ao[k]*c2;
    m = mn;
  }
  if (g == 0){
    float inv = (ssum > 0.f) ? 1.f/ssum : 0.f;
    float4 o0, o1;
    o0.x = eluf(acc[0]*inv + b2[q*8+0]); o0.y = eluf(acc[1]*inv + b2[q*8+1]);
    o0.z = eluf(acc[2]*inv + b2[q*8+2]); o0.w = eluf(acc[3]*inv + b2[q*8+3]);
    o1.x = eluf(acc[4]*inv + b2[q*8+4]); o1.y = eluf(acc[5]*inv + b2[q*8+5]);
    o1.z = eluf(acc[6]*inv + b2[q*8+6]); o1.w = eluf(acc[7]*inv + b2[q*8+7]);
    *reinterpret_cast<float4*>(hOut + (size_t)d*128 + q*8)     = o0;
    *reinterpret_cast<float4*>(hOut + (size_t)d*128 + q*8 + 4) = o1;
  }
}

// ---------------- node3 fused: 4-edge x 16-lane + head mean + final softmax ----------------
__global__ __launch_bounds__(256) void k_node3f(
    const int* __restrict__ rowptr, const int* __restrict__ esrc,
    const float* __restrict__ el, const float* __restrict__ er, const float* __restrict__ f,
    const float* __restrict__ pr, const int* __restrict__ flag,
    void* __restrict__ out, int N){
  const float* bc = pr + 86784;
  int t = threadIdx.x;
  int wid = t >> 6, lane = t & 63;
  int q = lane & 15, g = lane >> 4;
  int h = q >> 2;                      // head of this lane's dims
  int d = blockIdx.x*4 + wid;
  if (d >= N) return;
  int r0 = rowptr[d], r1 = rowptr[d+1];
  float erh = er[(size_t)d*4 + h];
  float m = -INFINITY, ssum = 0.f;
  float acc[8] = {0.f,0.f,0.f,0.f,0.f,0.f,0.f,0.f};
  for (int i = r0 + g; i < r1; i += 4){
    int s = esrc[i];
    float sc = lrelu(el[(size_t)s*4 + h] + erh);
    const float4 f0 = *reinterpret_cast<const float4*>(f + (size_t)s*128 + q*8);
    const float4 f1 = *reinterpret_cast<const float4*>(f + (size_t)s*128 + q*8 + 4);
    float mn = fmaxf(m, sc);
    float cor = __expf(m - mn);
    float w = __expf(sc - mn);
    ssum = ssum*cor + w;
    acc[0]=acc[0]*cor + w*f0.x; acc[1]=acc[1]*cor + w*f0.y;
    acc[2]=acc[2]*cor + w*f0.z; acc[3]=acc[3]*cor + w*f0.w;
    acc[4]=acc[4]*cor + w*f1.x; acc[5]=acc[5]*cor + w*f1.y;
    acc[6]=acc[6]*cor + w*f1.z; acc[7]=acc[7]*cor + w*f1.w;
    m = mn;
  }
  #pragma unroll
  for (int off = 16; off <= 32; off <<= 1){
    float mo  = __shfl_xor(m, off);
    float sso = __shfl_xor(ssum, off);
    float ao[8];
    #pragma unroll
    for (int k=0;k<8;++k) ao[k] = __shfl_xor(acc[k], off);
    float mn = fmaxf(m, mo);
    float c1 = (m  > -1e30f) ? __expf(m  - mn) : 0.f;
    float c2 = (mo > -1e30f) ? __expf(mo - mn) : 0.f;
    ssum = ssum*c1 + sso*c2;
    #pragma unroll
    for (int k=0;k<8;++k) acc[k] = acc[k]*c1 + ao[k]*c2;
    m = mn;
  }
  float inv = (ssum > 0.f) ? 1.f/ssum : 0.f;
  float v[8];
  #pragma unroll
  for (int k=0;k<8;++k) v[k] = acc[k]*inv + bc[q*8+k];
  // head mean: classes c = (q&3)*8+k live on lanes {c/8, 4+c/8, 8+c/8, 12+c/8}
  #pragma unroll
  for (int k=0;k<8;++k){
    v[k] += __shfl_xor(v[k], 4);
    v[k] += __shfl_xor(v[k], 8);
    v[k] *= 0.25f;
  }
  // softmax over 32 classes spread across 4-lane orbit (xor 1,2), 8 per lane
  float mm = fmaxf(fmaxf(fmaxf(v[0],v[1]),fmaxf(v[2],v[3])),
                   fmaxf(fmaxf(v[4],v[5]),fmaxf(v[6],v[7])));
  mm = fmaxf(mm, __shfl_xor(mm, 1));
  mm = fmaxf(mm, __shfl_xor(mm, 2));
  float ex[8]; float se = 0.f;
  #pragma unroll
  for (int k=0;k<8;++k){ ex[k] = __expf(v[k]-mm); se += ex[k]; }
  se += __shfl_xor(se, 1);
  se += __shfl_xor(se, 2);
  float rs = 1.f/se;
  if (lane < 4){
    if (flag[0]){
      float4 o0 = make_float4(ex[0]*rs, ex[1]*rs, ex[2]*rs, ex[3]*rs);
      float4 o1 = make_float4(ex[4]*rs, ex[5]*rs, ex[6]*rs, ex[7]*rs);
      *reinterpret_cast<float4*>((float*)out + (size_t)d*32 + q*8)     = o0;
      *reinterpret_cast<float4*>((float*)out + (size_t)d*32 + q*8 + 4) = o1;
    } else {
      u32* o = (u32*)out + (size_t)d*16 + q*4;
      o[0] = (u32)f2bf(ex[0]*rs) | ((u32)f2bf(ex[1]*rs) << 16);
      o[1] = (u32)f2bf(ex[2]*rs) | ((u32)f2bf(ex[3]*rs) << 16);
      o[2] = (u32)f2bf(ex[4]*rs) | ((u32)f2bf(ex[5]*rs) << 16);
      o[3] = (u32)f2bf(ex[6]*rs) | ((u32)f2bf(ex[7]*rs) << 16);
    }
  }
}

// ---------------- GEMM: out = X @ W (optionally two W's), all f32 ----------------
template<bool TWO>
__global__ __launch_bounds__(256) void k_gemm(
    const float* __restrict__ X, const float* __restrict__ Ws, const float* __restrict__ Wd,
    float* __restrict__ outS, float* __restrict__ outD, int N){
  __shared__ float xs[64*128];
  int t = threadIdx.x;
  int row0 = blockIdx.x * 64;
  #pragma unroll
  for (int i = 0; i < 8; ++i){
    int idx = t + i*256;            // float4 index, 0..2047
    int r = idx >> 5;
    int c4 = idx & 31;
    float4 v = make_float4(0.f,0.f,0.f,0.f);
    if (row0 + r < N) v = *reinterpret_cast<const float4*>(X + (size_t)(row0+r)*128 + c4*4);
    *reinterpret_cast<float4*>(&xs[r*128 + c4*4]) = v;
  }
  __syncthreads();
  int rg = t >> 5, jg = t & 31;
  float accS[8][4]; float accD[8][4];
  #pragma unroll
  for (int r=0;r<8;++r)
    #pragma unroll
    for (int c=0;c<4;++c){ accS[r][c]=0.f; accD[r][c]=0.f; }
  const float* xbase = &xs[(rg*8)*128];
  for (int k4 = 0; k4 < 32; ++k4){
    float4 xv[8];
    #pragma unroll
    for (int r=0;r<8;++r) xv[r] = *reinterpret_cast<const float4*>(xbase + r*128 + k4*4);
    #pragma unroll
    for (int kk=0;kk<4;++kk){
      int k = k4*4 + kk;
      float4 ws4 = *reinterpret_cast<const float4*>(Ws + k*128 + jg*4);
      #pragma unroll
      for (int r=0;r<8;++r){
        float xk = (kk==0)?xv[r].x:(kk==1)?xv[r].y:(kk==2)?xv[r].z:xv[r].w;
        accS[r][0] += xk*ws4.x; accS[r][1] += xk*ws4.y;
        accS[r][2] += xk*ws4.z; accS[r][3] += xk*ws4.w;
      }
      if (TWO){
        float4 wd4 = *reinterpret_cast<const float4*>(Wd + k*128 + jg*4);
        #pragma unroll
        for (int r=0;r<8;++r){
          float xk = (kk==0)?xv[r].x:(kk==1)?xv[r].y:(kk==2)?xv[r].z:xv[r].w;
          accD[r][0] += xk*wd4.x; accD[r][1] += xk*wd4.y;
          accD[r][2] += xk*wd4.z; accD[r][3] += xk*wd4.w;
        }
      }
    }
  }
  #pragma unroll
  for (int r=0;r<8;++r){
    int row = row0 + rg*8 + r;
    if (row < N){
      *reinterpret_cast<float4*>(outS + (size_t)row*128 + jg*4) =
          make_float4(accS[r][0],accS[r][1],accS[r][2],accS[r][3]);
      if (TWO){
        *reinterpret_cast<float4*>(outD + (size_t)row*128 + jg*4) =
            make_float4(accD[r][0],accD[r][1],accD[r][2],accD[r][3]);
      }
    }
  }
}

// ---------------- per-node el/er for GAT v1 ----------------
__global__ void k_el(const float* __restrict__ f, const float* __restrict__ pr,
                     float* __restrict__ el, float* __restrict__ er, int N){
  const float* al = pr + 86528;
  const float* ar = pr + 86656;
  int g = blockIdx.x*256 + threadIdx.x;
  if (g >= N*4) return;
  int n = g >> 2, h = g & 3;
  const float4* f4 = reinterpret_cast<const float4*>(f + (size_t)n*128 + h*32);
  const float4* al4 = reinterpret_cast<const float4*>(al + h*32);
  const float4* ar4 = reinterpret_cast<const float4*>(ar + h*32);
  float aL=0.f, aR=0.f;
  #pragma unroll
  for (int q=0;q<8;++q){
    float4 x = f4[q];
    float4 u = al4[q], v = ar4[q];
    aL += u.x*x.x + u.y*x.y + u.z*x.z + u.w*x.w;
    aR += v.x*x.x + v.y*x.y + v.z*x.z + v.w*x.w;
  }
  el[g] = aL; er[g] = aR;
}

extern "C" void kernel_launch(void* const* d_in, const int* in_sizes, int n_in,
                              void* d_out, int out_size, void* d_ws, size_t ws_size,
                              hipStream_t stream){
  const int* in_feat = (const int*)d_in[0];
  const int* src     = (const int*)d_in[1];
  const int* dstA    = (const int*)d_in[2];
  const int N = in_sizes[0];
  const int E = in_sizes[1];

  char* p = (char*)d_ws;
  auto alloc = [&](size_t bytes)->char*{
    char* r = p; p += (bytes + 255) & ~(size_t)255; return r;
  };
  float* big0   = (float*)alloc((size_t)N*128*4);   // fs2, then f3
  float* big1   = (float*)alloc((size_t)N*128*4);   // fd2
  float* big2   = (float*)alloc((size_t)N*128*4);   // h1, then h2
  int*   deg    = (int*)alloc((size_t)N*4);
  int*   rowptr = (int*)alloc((size_t)(N+1)*4);
  int*   cursor = (int*)alloc((size_t)N*4);
  int*   bsum   = (int*)alloc(1024*4);
  int*   boff   = (int*)alloc(1024*4);
  int*   esrc   = (int*)alloc((size_t)E*4);
  int*   evf    = (int*)alloc((size_t)E*4);
  float* Ts     = (float*)alloc(4096*4);
  float* Td     = (float*)alloc(4096*4);
  float* S1     = (float*)alloc(4096*4);
  float* el     = (float*)alloc((size_t)N*4*4);
  float* er     = (float*)alloc((size_t)N*4*4);
  float* parena = (float*)alloc(86912*4);
  int*   flag   = (int*)alloc(256);

  // dtype probe + param conversion
  k_probe<<<1,64,0,stream>>>((const u16*)d_in[4], flag);
  Params13 P;
  const int sz[13]  = {4096,16384,16384,128,128,16384,16384,128,128,16384,128,128,128};
  int off = 0;
  for (int t = 0; t < 13; ++t){
    P.src[t] = d_in[3 + t];
    P.n[t] = sz[t];
    P.off[t] = off;
    off += sz[t];
  }
  k_cvt<<<dim3(64,13),256,0,stream>>>(P, flag, parena);

  hipMemsetAsync(deg, 0, (size_t)N*4, stream);
  int gE = (E + 255)/256;
  int nb = (N + 255)/256;
  k_deg<<<gE,256,0,stream>>>(dstA, deg, E);
  k_bsum<<<nb,256,0,stream>>>(deg, bsum, N);
  k_scanb<<<1,64,0,stream>>>(bsum, boff, rowptr, nb, N);
  k_scan2<<<nb,256,0,stream>>>(deg, boff, rowptr, cursor, N);
  k_scatter<<<gE,256,0,stream>>>(src, dstA, in_feat, cursor, esrc, evf, E);

  k_tinyA<<<16,256,0,stream>>>(parena, Ts, Td);
  k_tinyB<<<16,256,0,stream>>>(Ts, Td, parena, S1);

  float* h1 = big2;
  int gN64 = (N + 63)/64;
  k_node1<<<gN64,256,0,stream>>>(rowptr, evf, in_feat, Ts, S1, parena, h1, N);

  int gG = (N + 63)/64;
  float* fs2 = big0; float* fd2 = big1;
  k_gemm<true><<<gG,256,0,stream>>>(h1, parena + 37120, parena + 53504, fs2, fd2, N);

  int gN4 = (N + 3)/4;
  float* h2 = big2;      // h1 consumed by gemm; reuse
  k_node2f<<<gN4,256,0,stream>>>(rowptr, esrc, fs2, fd2, parena, h2, N);

  float* f3 = big0;      // fs2 dead after node2f
  k_gemm<false><<<gG,256,0,stream>>>(h2, parena + 70144, nullptr, f3, nullptr, N);

  int gEl = (int)(((size_t)N*4 + 255)/256);
  k_el<<<gEl,256,0,stream>>>(f3, parena, el, er, N);

  k_node3f<<<gN4,256,0,stream>>>(rowptr, esrc, el, er, f3, parena, flag, d_out, N);
}

// Round 5
// 403.891 us; speedup vs baseline: 2.2909x; 1.0178x over previous
//
#include <hip/hip_runtime.h>
#include <hip/hip_bf16.h>

typedef unsigned short u16;
typedef unsigned int u32;

#define NEG_SLOPE 0.2f

__device__ __forceinline__ float bf2f(u16 u){
  union { u32 i; float f; } c; c.i = ((u32)u) << 16; return c.f;
}
__device__ __forceinline__ u16 f2bf(float f){
  __hip_bfloat16 h = __float2bfloat16(f);
  u16 u; __builtin_memcpy(&u, &h, 2); return u;
}
__device__ __forceinline__ float lrelu(float x){
  return fmaxf(x, 0.f) + NEG_SLOPE * fminf(x, 0.f);
}
__device__ __forceinline__ float eluf(float x){
  return x > 0.f ? x : (__expf(x) - 1.f);
}

// ---------------- dtype probe ----------------
__global__ void k_probe(const u16* __restrict__ w, int* __restrict__ flag){
  int t = threadIdx.x;
  int hit = 0;
  for (int i = t; i < 4096; i += 64){
    u16 v = w[i];
    int e = (v >> 7) & 0xFF;
    if (e >= 200) hit = 1;
  }
  unsigned long long b = __ballot(hit);
  if (t == 0) flag[0] = b ? 1 : 0;   // 1 => float32 data
}

// ---------------- param conversion to f32 arena ----------------
struct Params13 {
  const void* src[13];
  int off[13];
  int n[13];
};

__global__ void k_cvt(Params13 P, const int* __restrict__ flag, float* __restrict__ dst){
  int t = blockIdx.y;
  int i = blockIdx.x*256 + threadIdx.x;
  if (i >= P.n[t]) return;
  int f = flag[0];
  float v = f ? ((const float*)P.src[t])[i] : bf2f(((const u16*)P.src[t])[i]);
  dst[P.off[t] + i] = v;
}

// ---------------- histogram of src-types per dst ----------------
__global__ void k_hist(const int* __restrict__ src, const int* __restrict__ dst,
                       const int* __restrict__ vf, u32* __restrict__ H, int E){
  int i = blockIdx.x*256 + threadIdx.x;
  if (i < E){
    atomicAdd(&H[(size_t)dst[i]*32 + vf[src[i]]], 1u);
  }
}

// deg[i] = row-sum of H; block sums for scan
__global__ __launch_bounds__(256) void k_bsumH(const u32* __restrict__ H,
                                               int* __restrict__ deg,
                                               int* __restrict__ bsum, int N){
  __shared__ int ws[4];
  int t = threadIdx.x;
  int i = blockIdx.x*256 + t;
  int v = 0;
  if (i < N){
    const int4* r = reinterpret_cast<const int4*>(H + (size_t)i*32);
    #pragma unroll
    for (int k=0;k<8;++k){ int4 a = r[k]; v += a.x+a.y+a.z+a.w; }
    deg[i] = v;
  }
  #pragma unroll
  for (int off=32; off>=1; off>>=1) v += __shfl_down(v, off);
  if ((t & 63) == 0) ws[t>>6] = v;
  __syncthreads();
  if (t == 0) bsum[blockIdx.x] = ws[0]+ws[1]+ws[2]+ws[3];
}

__global__ void k_scanb(const int* __restrict__ bsum, int* __restrict__ boff,
                        int* __restrict__ rowptr, int nb, int N){
  int l = threadIdx.x;
  int carry = 0;
  int nChunk = (nb + 63) >> 6;
  for (int c = 0; c < nChunk; ++c){
    int idx = (c << 6) + l;
    int v = (idx < nb) ? bsum[idx] : 0;
    int x = v;
    #pragma unroll
    for (int off=1; off<64; off<<=1){
      int y = __shfl_up(x, off);
      if (l >= off) x += y;
    }
    if (idx < nb) boff[idx] = carry + x - v;
    carry += __shfl(x, 63);
  }
  if (l == 0) rowptr[N] = carry;
}

__global__ __launch_bounds__(256) void k_scan2(const int* __restrict__ deg,
                                               const int* __restrict__ boff,
                                               int* __restrict__ rowptr,
                                               int* __restrict__ cursor, int N){
  __shared__ int ws[4];
  int t = threadIdx.x;
  int i = blockIdx.x*256 + t;
  int lane = t & 63, wid = t >> 6;
  int v = (i < N) ? deg[i] : 0;
  int x = v;
  #pragma unroll
  for (int off=1; off<64; off<<=1){
    int y = __shfl_up(x, off);
    if (lane >= off) x += y;
  }
  if (lane == 63) ws[wid] = x;
  __syncthreads();
  int woff = 0;
  #pragma unroll
  for (int w=0; w<4; ++w) woff += (w < wid) ? ws[w] : 0;
  int excl = boff[blockIdx.x] + woff + x - v;
  if (i < N){ rowptr[i] = excl; cursor[i] = excl; }
}

__global__ void k_scatter(const int* __restrict__ src, const int* __restrict__ dst,
                          int* __restrict__ cursor, int* __restrict__ esrc, int E){
  int i = blockIdx.x*256 + threadIdx.x;
  if (i < E){
    int d = dst[i];
    int s = src[i];
    int pos = atomicAdd(&cursor[d], 1);
    esrc[pos] = s;
  }
}

// ---------------- layer-1 tiny tables ----------------
__global__ void k_tinyA(const float* __restrict__ pr,
                        float* __restrict__ Ts, float* __restrict__ Td){
  const float* emb = pr + 0;
  const float* W1s = pr + 4096;
  const float* W1d = pr + 20480;
  int g = blockIdx.x*256 + threadIdx.x;   // 0..4095
  int v = g >> 7, j = g & 127;
  float as = 0.f, ad = 0.f;
  for (int k = 0; k < 128; ++k){
    float e = emb[v*128 + k];
    as += e * W1s[k*128 + j];
    ad += e * W1d[k*128 + j];
  }
  Ts[g] = as; Td[g] = ad;
}

// S1[vd][vs][h] = sum_d a1[h][d]*leaky(Ts[vs][h*32+d]+Td[vd][h*32+d])
__global__ void k_tinyB(const float* __restrict__ Ts, const float* __restrict__ Td,
                        const float* __restrict__ pr, float* __restrict__ S1){
  const float* a1 = pr + 36864;
  int g = blockIdx.x*256 + threadIdx.x;   // vd*128 + vs*4 + h
  int vd = g >> 7, vs = (g >> 2) & 31, h = g & 3;
  float acc = 0.f;
  for (int dd = 0; dd < 32; ++dd){
    float x = Ts[vs*128 + h*32 + dd] + Td[vd*128 + h*32 + dd];
    acc += a1[h*32 + dd] * lrelu(x);
  }
  S1[g] = acc;
}

// ---------------- node1 via histogram: exact grouped softmax ----------------
__global__ __launch_bounds__(256) void k_node1h(
    const u32* __restrict__ H, const int* __restrict__ vf,
    const float* __restrict__ Ts, const float* __restrict__ S1,
    const float* __restrict__ pr, float* __restrict__ hOut, int N){
  const float* b1 = pr + 36992;
  __shared__ float TsL[4096];
  __shared__ float S1L[4096];
  __shared__ float wbuf[4][32][4];
  int t = threadIdx.x;
  for (int i = t; i < 4096; i += 256){ TsL[i] = Ts[i]; S1L[i] = S1[i]; }
  __syncthreads();
  int wid = t >> 6, lane = t & 63;
  int h = lane >> 4;
  float bx = b1[lane*2], by = b1[lane*2+1];
  int base = blockIdx.x * 64;
  for (int dd = wid; dd < 64; dd += 4){
    int d = base + dd;
    if (d >= N) break;
    int tt = vf[d];
    int cnt = 0;
    float4 sc = make_float4(0.f,0.f,0.f,0.f);
    if (lane < 32){
      cnt = (int)H[(size_t)d*32 + lane];
      sc = *reinterpret_cast<const float4*>(&S1L[tt*128 + lane*4]);
    }
    bool valid = (lane < 32) && (cnt > 0);
    float4 mv = valid ? sc : make_float4(-INFINITY,-INFINITY,-INFINITY,-INFINITY);
    #pragma unroll
    for (int off=1; off<32; off<<=1){
      mv.x = fmaxf(mv.x, __shfl_xor(mv.x, off));
      mv.y = fmaxf(mv.y, __shfl_xor(mv.y, off));
      mv.z = fmaxf(mv.z, __shfl_xor(mv.z, off));
      mv.w = fmaxf(mv.w, __shfl_xor(mv.w, off));
    }
    float4 w4 = make_float4(0.f,0.f,0.f,0.f);
    if (valid){
      float cf = (float)cnt;
      w4.x = cf * __expf(sc.x - mv.x);
      w4.y = cf * __expf(sc.y - mv.y);
      w4.z = cf * __expf(sc.z - mv.z);
      w4.w = cf * __expf(sc.w - mv.w);
    }
    float4 sv = w4;
    #pragma unroll
    for (int off=1; off<32; off<<=1){
      sv.x += __shfl_xor(sv.x, off);
      sv.y += __shfl_xor(sv.y, off);
      sv.z += __shfl_xor(sv.z, off);
      sv.w += __shfl_xor(sv.w, off);
    }
    float sh = (h==0)?sv.x:(h==1)?sv.y:(h==2)?sv.z:sv.w;
    sh += __shfl_xor(sh, 32);
    if (lane < 32) *reinterpret_cast<float4*>(&wbuf[wid][lane][0]) = w4;
    __builtin_amdgcn_wave_barrier();
    float inv = (sh > 0.f) ? 1.f/sh : 0.f;
    float ax = 0.f, ay = 0.f;
    #pragma unroll 8
    for (int v=0; v<32; ++v){
      float wv = wbuf[wid][v][h];
      const float2 f = *reinterpret_cast<const float2*>(&TsL[v*128 + lane*2]);
      ax += wv * f.x; ay += wv * f.y;
    }
    float2 o;
    o.x = eluf(ax*inv + bx);
    o.y = eluf(ay*inv + by);
    *reinterpret_cast<float2*>(&hOut[(size_t)d*128 + lane*2]) = o;
  }
}

// ---------------- node2 fused: 4-edge x 16-lane online softmax ----------------
__global__ __launch_bounds__(256) void k_node2f(
    const int* __restrict__ rowptr, const int* __restrict__ esrc,
    const float* __restrict__ fs, const float* __restrict__ fd,
    const float* __restrict__ pr, float* __restrict__ hOut, int N){
  const float* a2 = pr + 69888;
  const float* b2 = pr + 70016;
  int t = threadIdx.x;
  int wid = t >> 6, lane = t & 63;
  int q = lane & 15, g = lane >> 4;   // lane q holds dims q*8..q*8+7; group g = edge stream
  int d = blockIdx.x*4 + wid;
  if (d >= N) return;
  int r0 = rowptr[d], r1 = rowptr[d+1];
  const float4 a2lo = *reinterpret_cast<const float4*>(a2 + q*8);
  const float4 a2hi = *reinterpret_cast<const float4*>(a2 + q*8 + 4);
  const float4 fdlo = *reinterpret_cast<const float4*>(fd + (size_t)d*128 + q*8);
  const float4 fdhi = *reinterpret_cast<const float4*>(fd + (size_t)d*128 + q*8 + 4);
  float m = -INFINITY, ssum = 0.f;
  float acc[8] = {0.f,0.f,0.f,0.f,0.f,0.f,0.f,0.f};
  for (int i = r0 + g; i < r1; i += 4){
    int s = esrc[i];
    const float4 f0 = *reinterpret_cast<const float4*>(fs + (size_t)s*128 + q*8);
    const float4 f1 = *reinterpret_cast<const float4*>(fs + (size_t)s*128 + q*8 + 4);
    float p = a2lo.x*lrelu(f0.x+fdlo.x) + a2lo.y*lrelu(f0.y+fdlo.y)
            + a2lo.z*lrelu(f0.z+fdlo.z) + a2lo.w*lrelu(f0.w+fdlo.w)
            + a2hi.x*lrelu(f1.x+fdhi.x) + a2hi.y*lrelu(f1.y+fdhi.y)
            + a2hi.z*lrelu(f1.z+fdhi.z) + a2hi.w*lrelu(f1.w+fdhi.w);
    p += __shfl_xor(p, 1); p += __shfl_xor(p, 2);   // head = 4-lane slice
    float mn = fmaxf(m, p);
    float cor = __expf(m - mn);
    float w = __expf(p - mn);
    ssum = ssum*cor + w;
    acc[0]=acc[0]*cor + w*f0.x; acc[1]=acc[1]*cor + w*f0.y;
    acc[2]=acc[2]*cor + w*f0.z; acc[3]=acc[3]*cor + w*f0.w;
    acc[4]=acc[4]*cor + w*f1.x; acc[5]=acc[5]*cor + w*f1.y;
    acc[6]=acc[6]*cor + w*f1.z; acc[7]=acc[7]*cor + w*f1.w;
    m = mn;
  }
  // merge the 4 groups' online states
  #pragma unroll
  for (int off = 16; off <= 32; off <<= 1){
    float mo  = __shfl_xor(m, off);
    float sso = __shfl_xor(ssum, off);
    float ao[8];
    #pragma unroll
    for (int k=0;k<8;++k) ao[k] = __shfl_xor(acc[k], off);
    float mn = fmaxf(m, mo);
    float c1 = (m  > -1e30f) ? __expf(m  - mn) : 0.f;
    float c2 = (mo > -1e30f) ? __expf(mo - mn) : 0.f;
    ssum = ssum*c1 + sso*c2;
    #pragma unroll
    for (int k=0;k<8;++k) acc[k] = acc[k]*c1 + ao[k]*c2;
    m = mn;
  }
  if (g == 0){
    float inv = (ssum > 0.f) ? 1.f/ssum : 0.f;
    float4 o0, o1;
    o0.x = eluf(acc[0]*inv + b2[q*8+0]); o0.y = eluf(acc[1]*inv + b2[q*8+1]);
    o0.z = eluf(acc[2]*inv + b2[q*8+2]); o0.w = eluf(acc[3]*inv + b2[q*8+3]);
    o1.x = eluf(acc[4]*inv + b2[q*8+4]); o1.y = eluf(acc[5]*inv + b2[q*8+5]);
    o1.z = eluf(acc[6]*inv + b2[q*8+6]); o1.w = eluf(acc[7]*inv + b2[q*8+7]);
    *reinterpret_cast<float4*>(hOut + (size_t)d*128 + q*8)     = o0;
    *reinterpret_cast<float4*>(hOut + (size_t)d*128 + q*8 + 4) = o1;
  }
}

// ---------------- node3 fused: 4-edge x 16-lane + head mean + final softmax ----------------
__global__ __launch_bounds__(256) void k_node3f(
    const int* __restrict__ rowptr, const int* __restrict__ esrc,
    const float* __restrict__ el, const float* __restrict__ er, const float* __restrict__ f,
    const float* __restrict__ pr, const int* __restrict__ flag,
    void* __restrict__ out, int N){
  const float* bc = pr + 86784;
  int t = threadIdx.x;
  int wid = t >> 6, lane = t & 63;
  int q = lane & 15, g = lane >> 4;
  int h = q >> 2;                      // head of this lane's dims
  int d = blockIdx.x*4 + wid;
  if (d >= N) return;
  int r0 = rowptr[d], r1 = rowptr[d+1];
  float erh = er[(size_t)d*4 + h];
  float m = -INFINITY, ssum = 0.f;
  float acc[8] = {0.f,0.f,0.f,0.f,0.f,0.f,0.f,0.f};
  for (int i = r0 + g; i < r1; i += 4){
    int s = esrc[i];
    float sc = lrelu(el[(size_t)s*4 + h] + erh);
    const float4 f0 = *reinterpret_cast<const float4*>(f + (size_t)s*128 + q*8);
    const float4 f1 = *reinterpret_cast<const float4*>(f + (size_t)s*128 + q*8 + 4);
    float mn = fmaxf(m, sc);
    float cor = __expf(m - mn);
    float w = __expf(sc - mn);
    ssum = ssum*cor + w;
    acc[0]=acc[0]*cor + w*f0.x; acc[1]=acc[1]*cor + w*f0.y;
    acc[2]=acc[2]*cor + w*f0.z; acc[3]=acc[3]*cor + w*f0.w;
    acc[4]=acc[4]*cor + w*f1.x; acc[5]=acc[5]*cor + w*f1.y;
    acc[6]=acc[6]*cor + w*f1.z; acc[7]=acc[7]*cor + w*f1.w;
    m = mn;
  }
  #pragma unroll
  for (int off = 16; off <= 32; off <<= 1){
    float mo  = __shfl_xor(m, off);
    float sso = __shfl_xor(ssum, off);
    float ao[8];
    #pragma unroll
    for (int k=0;k<8;++k) ao[k] = __shfl_xor(acc[k], off);
    float mn = fmaxf(m, mo);
    float c1 = (m  > -1e30f) ? __expf(m  - mn) : 0.f;
    float c2 = (mo > -1e30f) ? __expf(mo - mn) : 0.f;
    ssum = ssum*c1 + sso*c2;
    #pragma unroll
    for (int k=0;k<8;++k) acc[k] = acc[k]*c1 + ao[k]*c2;
    m = mn;
  }
  float inv = (ssum > 0.f) ? 1.f/ssum : 0.f;
  float v[8];
  #pragma unroll
  for (int k=0;k<8;++k) v[k] = acc[k]*inv + bc[q*8+k];
  // head mean: classes c = (q&3)*8+k live on lanes {c/8, 4+c/8, 8+c/8, 12+c/8}
  #pragma unroll
  for (int k=0;k<8;++k){
    v[k] += __shfl_xor(v[k], 4);
    v[k] += __shfl_xor(v[k], 8);
    v[k] *= 0.25f;
  }
  // softmax over 32 classes spread across 4-lane orbit (xor 1,2), 8 per lane
  float mm = fmaxf(fmaxf(fmaxf(v[0],v[1]),fmaxf(v[2],v[3])),
                   fmaxf(fmaxf(v[4],v[5]),fmaxf(v[6],v[7])));
  mm = fmaxf(mm, __shfl_xor(mm, 1));
  mm = fmaxf(mm, __shfl_xor(mm, 2));
  float ex[8]; float se = 0.f;
  #pragma unroll
  for (int k=0;k<8;++k){ ex[k] = __expf(v[k]-mm); se += ex[k]; }
  se += __shfl_xor(se, 1);
  se += __shfl_xor(se, 2);
  float rs = 1.f/se;
  if (lane < 4){
    if (flag[0]){
      float4 o0 = make_float4(ex[0]*rs, ex[1]*rs, ex[2]*rs, ex[3]*rs);
      float4 o1 = make_float4(ex[4]*rs, ex[5]*rs, ex[6]*rs, ex[7]*rs);
      *reinterpret_cast<float4*>((float*)out + (size_t)d*32 + q*8)     = o0;
      *reinterpret_cast<float4*>((float*)out + (size_t)d*32 + q*8 + 4) = o1;
    } else {
      u32* o = (u32*)out + (size_t)d*16 + q*4;
      o[0] = (u32)f2bf(ex[0]*rs) | ((u32)f2bf(ex[1]*rs) << 16);
      o[1] = (u32)f2bf(ex[2]*rs) | ((u32)f2bf(ex[3]*rs) << 16);
      o[2] = (u32)f2bf(ex[4]*rs) | ((u32)f2bf(ex[5]*rs) << 16);
      o[3] = (u32)f2bf(ex[6]*rs) | ((u32)f2bf(ex[7]*rs) << 16);
    }
  }
}

// ---------------- GEMM: out = X @ W (optionally two W's), all f32 ----------------
template<bool TWO>
__global__ __launch_bounds__(256) void k_gemm(
    const float* __restrict__ X, const float* __restrict__ Ws, const float* __restrict__ Wd,
    float* __restrict__ outS, float* __restrict__ outD, int N){
  __shared__ float xs[64*128];
  int t = threadIdx.x;
  int row0 = blockIdx.x * 64;
  #pragma unroll
  for (int i = 0; i < 8; ++i){
    int idx = t + i*256;            // float4 index, 0..2047
    int r = idx >> 5;
    int c4 = idx & 31;
    float4 v = make_float4(0.f,0.f,0.f,0.f);
    if (row0 + r < N) v = *reinterpret_cast<const float4*>(X + (size_t)(row0+r)*128 + c4*4);
    *reinterpret_cast<float4*>(&xs[r*128 + c4*4]) = v;
  }
  __syncthreads();
  int rg = t >> 5, jg = t & 31;
  float accS[8][4]; float accD[8][4];
  #pragma unroll
  for (int r=0;r<8;++r)
    #pragma unroll
    for (int c=0;c<4;++c){ accS[r][c]=0.f; accD[r][c]=0.f; }
  const float* xbase = &xs[(rg*8)*128];
  for (int k4 = 0; k4 < 32; ++k4){
    float4 xv[8];
    #pragma unroll
    for (int r=0;r<8;++r) xv[r] = *reinterpret_cast<const float4*>(xbase + r*128 + k4*4);
    #pragma unroll
    for (int kk=0;kk<4;++kk){
      int k = k4*4 + kk;
      float4 ws4 = *reinterpret_cast<const float4*>(Ws + k*128 + jg*4);
      #pragma unroll
      for (int r=0;r<8;++r){
        float xk = (kk==0)?xv[r].x:(kk==1)?xv[r].y:(kk==2)?xv[r].z:xv[r].w;
        accS[r][0] += xk*ws4.x; accS[r][1] += xk*ws4.y;
        accS[r][2] += xk*ws4.z; accS[r][3] += xk*ws4.w;
      }
      if (TWO){
        float4 wd4 = *reinterpret_cast<const float4*>(Wd + k*128 + jg*4);
        #pragma unroll
        for (int r=0;r<8;++r){
          float xk = (kk==0)?xv[r].x:(kk==1)?xv[r].y:(kk==2)?xv[r].z:xv[r].w;
          accD[r][0] += xk*wd4.x; accD[r][1] += xk*wd4.y;
          accD[r][2] += xk*wd4.z; accD[r][3] += xk*wd4.w;
        }
      }
    }
  }
  #pragma unroll
  for (int r=0;r<8;++r){
    int row = row0 + rg*8 + r;
    if (row < N){
      *reinterpret_cast<float4*>(outS + (size_t)row*128 + jg*4) =
          make_float4(accS[r][0],accS[r][1],accS[r][2],accS[r][3]);
      if (TWO){
        *reinterpret_cast<float4*>(outD + (size_t)row*128 + jg*4) =
            make_float4(accD[r][0],accD[r][1],accD[r][2],accD[r][3]);
      }
    }
  }
}

// ---------------- per-node el/er for GAT v1 ----------------
__global__ void k_el(const float* __restrict__ f, const float* __restrict__ pr,
                     float* __restrict__ el, float* __restrict__ er, int N){
  const float* al = pr + 86528;
  const float* ar = pr + 86656;
  int g = blockIdx.x*256 + threadIdx.x;
  if (g >= N*4) return;
  int n = g >> 2, h = g & 3;
  const float4* f4 = reinterpret_cast<const float4*>(f + (size_t)n*128 + h*32);
  const float4* al4 = reinterpret_cast<const float4*>(al + h*32);
  const float4* ar4 = reinterpret_cast<const float4*>(ar + h*32);
  float aL=0.f, aR=0.f;
  #pragma unroll
  for (int q=0;q<8;++q){
    float4 x = f4[q];
    float4 u = al4[q], v = ar4[q];
    aL += u.x*x.x + u.y*x.y + u.z*x.z + u.w*x.w;
    aR += v.x*x.x + v.y*x.y + v.z*x.z + v.w*x.w;
  }
  el[g] = aL; er[g] = aR;
}

extern "C" void kernel_launch(void* const* d_in, const int* in_sizes, int n_in,
                              void* d_out, int out_size, void* d_ws, size_t ws_size,
                              hipStream_t stream){
  const int* in_feat = (const int*)d_in[0];
  const int* src     = (const int*)d_in[1];
  const int* dstA    = (const int*)d_in[2];
  const int N = in_sizes[0];
  const int E = in_sizes[1];

  char* p = (char*)d_ws;
  auto alloc = [&](size_t bytes)->char*{
    char* r = p; p += (bytes + 255) & ~(size_t)255; return r;
  };
  float* big0   = (float*)alloc((size_t)N*128*4);   // H (hist), then fs2, then f3
  float* big1   = (float*)alloc((size_t)N*128*4);   // fd2
  float* big2   = (float*)alloc((size_t)N*128*4);   // h1, then h2
  int*   deg    = (int*)alloc((size_t)N*4);
  int*   rowptr = (int*)alloc((size_t)(N+1)*4);
  int*   cursor = (int*)alloc((size_t)N*4);
  int*   bsum   = (int*)alloc(1024*4);
  int*   boff   = (int*)alloc(1024*4);
  int*   esrc   = (int*)alloc((size_t)E*4);
  float* Ts     = (float*)alloc(4096*4);
  float* Td     = (float*)alloc(4096*4);
  float* S1     = (float*)alloc(4096*4);
  float* el     = (float*)alloc((size_t)N*4*4);
  float* er     = (float*)alloc((size_t)N*4*4);
  float* parena = (float*)alloc(86912*4);
  int*   flag   = (int*)alloc(256);

  u32* H = (u32*)big0;   // alias: dead before fs2 is written

  // dtype probe + param conversion
  k_probe<<<1,64,0,stream>>>((const u16*)d_in[4], flag);
  Params13 P;
  const int sz[13]  = {4096,16384,16384,128,128,16384,16384,128,128,16384,128,128,128};
  int off = 0;
  for (int t = 0; t < 13; ++t){
    P.src[t] = d_in[3 + t];
    P.n[t] = sz[t];
    P.off[t] = off;
    off += sz[t];
  }
  k_cvt<<<dim3(64,13),256,0,stream>>>(P, flag, parena);

  hipMemsetAsync(H, 0, (size_t)N*32*4, stream);
  int gE = (E + 255)/256;
  int nb = (N + 255)/256;
  k_hist<<<gE,256,0,stream>>>(src, dstA, in_feat, H, E);
  k_bsumH<<<nb,256,0,stream>>>(H, deg, bsum, N);
  k_scanb<<<1,64,0,stream>>>(bsum, boff, rowptr, nb, N);
  k_scan2<<<nb,256,0,stream>>>(deg, boff, rowptr, cursor, N);
  k_scatter<<<gE,256,0,stream>>>(src, dstA, cursor, esrc, E);

  k_tinyA<<<16,256,0,stream>>>(parena, Ts, Td);
  k_tinyB<<<16,256,0,stream>>>(Ts, Td, parena, S1);

  float* h1 = big2;
  int gN64 = (N + 63)/64;
  k_node1h<<<gN64,256,0,stream>>>(H, in_feat, Ts, S1, parena, h1, N);

  int gG = (N + 63)/64;
  float* fs2 = big0; float* fd2 = big1;   // fs2 overwrites H (H dead now)
  k_gemm<true><<<gG,256,0,stream>>>(h1, parena + 37120, parena + 53504, fs2, fd2, N);

  int gN4 = (N + 3)/4;
  float* h2 = big2;      // h1 consumed by gemm; reuse
  k_node2f<<<gN4,256,0,stream>>>(rowptr, esrc, fs2, fd2, parena, h2, N);

  float* f3 = big0;      // fs2 dead after node2f
  k_gemm<false><<<gG,256,0,stream>>>(h2, parena + 70144, nullptr, f3, nullptr, N);

  int gEl = (int)(((size_t)N*4 + 255)/256);
  k_el<<<gEl,256,0,stream>>>(f3, parena, el, er, N);

  k_node3f<<<gN4,256,0,stream>>>(rowptr, esrc, el, er, f3, parena, flag, d_out, N);
}

// Round 6
// 385.262 us; speedup vs baseline: 2.4017x; 1.0484x over previous
//
#include <hip/hip_runtime.h>
#include <hip/hip_bf16.h>

typedef unsigned short u16;
typedef unsigned int u32;

#define NEG_SLOPE 0.2f

__device__ __forceinline__ float bf2f(u16 u){
  union { u32 i; float f; } c; c.i = ((u32)u) << 16; return c.f;
}
__device__ __forceinline__ u16 f2bf(float f){
  __hip_bfloat16 h = __float2bfloat16(f);
  u16 u; __builtin_memcpy(&u, &h, 2); return u;
}
__device__ __forceinline__ float lrelu(float x){
  return fmaxf(x, 0.f) + NEG_SLOPE * fminf(x, 0.f);
}
__device__ __forceinline__ float eluf(float x){
  return x > 0.f ? x : (__expf(x) - 1.f);
}

// ---------------- dtype probe ----------------
__global__ void k_probe(const u16* __restrict__ w, int* __restrict__ flag){
  int t = threadIdx.x;
  int hit = 0;
  for (int i = t; i < 4096; i += 64){
    u16 v = w[i];
    int e = (v >> 7) & 0xFF;
    if (e >= 200) hit = 1;
  }
  unsigned long long b = __ballot(hit);
  if (t == 0) flag[0] = b ? 1 : 0;   // 1 => float32 data
}

// ---------------- param conversion to f32 arena ----------------
struct Params13 {
  const void* src[13];
  int off[13];
  int n[13];
};

__global__ void k_cvt(Params13 P, const int* __restrict__ flag, float* __restrict__ dst){
  int t = blockIdx.y;
  int i = blockIdx.x*256 + threadIdx.x;
  if (i >= P.n[t]) return;
  int f = flag[0];
  float v = f ? ((const float*)P.src[t])[i] : bf2f(((const u16*)P.src[t])[i]);
  dst[P.off[t] + i] = v;
}

// ---------------- histogram of src-types per dst ----------------
__global__ void k_hist(const int* __restrict__ src, const int* __restrict__ dst,
                       const int* __restrict__ vf, u32* __restrict__ H, int E){
  int i = blockIdx.x*256 + threadIdx.x;
  if (i < E){
    atomicAdd(&H[(size_t)dst[i]*32 + vf[src[i]]], 1u);
  }
}

// deg[i] = row-sum of H; block sums for scan
__global__ __launch_bounds__(256) void k_bsumH(const u32* __restrict__ H,
                                               int* __restrict__ deg,
                                               int* __restrict__ bsum, int N){
  __shared__ int ws[4];
  int t = threadIdx.x;
  int i = blockIdx.x*256 + t;
  int v = 0;
  if (i < N){
    const int4* r = reinterpret_cast<const int4*>(H + (size_t)i*32);
    #pragma unroll
    for (int k=0;k<8;++k){ int4 a = r[k]; v += a.x+a.y+a.z+a.w; }
    deg[i] = v;
  }
  #pragma unroll
  for (int off=32; off>=1; off>>=1) v += __shfl_down(v, off);
  if ((t & 63) == 0) ws[t>>6] = v;
  __syncthreads();
  if (t == 0) bsum[blockIdx.x] = ws[0]+ws[1]+ws[2]+ws[3];
}

__global__ void k_scanb(const int* __restrict__ bsum, int* __restrict__ boff,
                        int* __restrict__ rowptr, int nb, int N){
  int l = threadIdx.x;
  int carry = 0;
  int nChunk = (nb + 63) >> 6;
  for (int c = 0; c < nChunk; ++c){
    int idx = (c << 6) + l;
    int v = (idx < nb) ? bsum[idx] : 0;
    int x = v;
    #pragma unroll
    for (int off=1; off<64; off<<=1){
      int y = __shfl_up(x, off);
      if (l >= off) x += y;
    }
    if (idx < nb) boff[idx] = carry + x - v;
    carry += __shfl(x, 63);
  }
  if (l == 0) rowptr[N] = carry;
}

__global__ __launch_bounds__(256) void k_scan2(const int* __restrict__ deg,
                                               const int* __restrict__ boff,
                                               int* __restrict__ rowptr,
                                               int* __restrict__ cursor, int N){
  __shared__ int ws[4];
  int t = threadIdx.x;
  int i = blockIdx.x*256 + t;
  int lane = t & 63, wid = t >> 6;
  int v = (i < N) ? deg[i] : 0;
  int x = v;
  #pragma unroll
  for (int off=1; off<64; off<<=1){
    int y = __shfl_up(x, off);
    if (lane >= off) x += y;
  }
  if (lane == 63) ws[wid] = x;
  __syncthreads();
  int woff = 0;
  #pragma unroll
  for (int w=0; w<4; ++w) woff += (w < wid) ? ws[w] : 0;
  int excl = boff[blockIdx.x] + woff + x - v;
  if (i < N){ rowptr[i] = excl; cursor[i] = excl; }
}

__global__ void k_scatter(const int* __restrict__ src, const int* __restrict__ dst,
                          int* __restrict__ cursor, int* __restrict__ esrc, int E){
  int i = blockIdx.x*256 + threadIdx.x;
  if (i < E){
    int d = dst[i];
    int s = src[i];
    int pos = atomicAdd(&cursor[d], 1);
    esrc[pos] = s;
  }
}

// ---------------- layer-1 tiny tables ----------------
__global__ void k_tinyA(const float* __restrict__ pr,
                        float* __restrict__ Ts, float* __restrict__ Td){
  const float* emb = pr + 0;
  const float* W1s = pr + 4096;
  const float* W1d = pr + 20480;
  int g = blockIdx.x*256 + threadIdx.x;   // 0..4095
  int v = g >> 7, j = g & 127;
  float as = 0.f, ad = 0.f;
  for (int k = 0; k < 128; ++k){
    float e = emb[v*128 + k];
    as += e * W1s[k*128 + j];
    ad += e * W1d[k*128 + j];
  }
  Ts[g] = as; Td[g] = ad;
}

// S1[vd][vs][h] = sum_d a1[h][d]*leaky(Ts[vs][h*32+d]+Td[vd][h*32+d])
__global__ void k_tinyB(const float* __restrict__ Ts, const float* __restrict__ Td,
                        const float* __restrict__ pr, float* __restrict__ S1){
  const float* a1 = pr + 36864;
  int g = blockIdx.x*256 + threadIdx.x;   // vd*128 + vs*4 + h
  int vd = g >> 7, vs = (g >> 2) & 31, h = g & 3;
  float acc = 0.f;
  for (int dd = 0; dd < 32; ++dd){
    float x = Ts[vs*128 + h*32 + dd] + Td[vd*128 + h*32 + dd];
    acc += a1[h*32 + dd] * lrelu(x);
  }
  S1[g] = acc;
}

// E[vd][vs][h] = exp(S1[vd][vs][h] - max_vs' S1[vd][vs'][h])
__global__ void k_tinyC(const float* __restrict__ S1, float* __restrict__ Ee){
  int g = blockIdx.x*256 + threadIdx.x;   // vd*128 + vs*4 + h
  int vd = g >> 7, h = g & 3;
  float M = -INFINITY;
  #pragma unroll 8
  for (int vs = 0; vs < 32; ++vs) M = fmaxf(M, S1[vd*128 + vs*4 + h]);
  Ee[g] = __expf(S1[g] - M);
}

// ---------------- node1 via histogram: exact grouped softmax, no exp/max in hot path ----------------
__global__ __launch_bounds__(256) void k_node1h(
    const u32* __restrict__ H, const int* __restrict__ vf,
    const float* __restrict__ Ts, const float* __restrict__ Ee,
    const float* __restrict__ pr, float* __restrict__ hOut, int N){
  const float* b1 = pr + 36992;
  __shared__ float TsL[4096];
  __shared__ float EL[4096];
  __shared__ float wbuf[4][32][4];
  int t = threadIdx.x;
  for (int i = t; i < 4096; i += 256){ TsL[i] = Ts[i]; EL[i] = Ee[i]; }
  __syncthreads();
  int wid = t >> 6, lane = t & 63;
  int h = lane >> 4;
  float bx = b1[lane*2], by = b1[lane*2+1];
  int base = blockIdx.x * 32;
  for (int dd = wid; dd < 32; dd += 4){
    int d = base + dd;
    if (d >= N) break;
    int tt = vf[d];
    float4 w4 = make_float4(0.f,0.f,0.f,0.f);
    if (lane < 32){
      float cf = (float)H[(size_t)d*32 + lane];
      const float4 e4 = *reinterpret_cast<const float4*>(&EL[tt*128 + lane*4]);
      w4.x = cf*e4.x; w4.y = cf*e4.y; w4.z = cf*e4.z; w4.w = cf*e4.w;
    }
    float4 sv = w4;
    #pragma unroll
    for (int off=1; off<32; off<<=1){
      sv.x += __shfl_xor(sv.x, off);
      sv.y += __shfl_xor(sv.y, off);
      sv.z += __shfl_xor(sv.z, off);
      sv.w += __shfl_xor(sv.w, off);
    }
    float sh = (h==0)?sv.x:(h==1)?sv.y:(h==2)?sv.z:sv.w;
    sh += __shfl_xor(sh, 32);
    if (lane < 32) *reinterpret_cast<float4*>(&wbuf[wid][lane][0]) = w4;
    __builtin_amdgcn_wave_barrier();
    float inv = (sh > 0.f) ? 1.f/sh : 0.f;
    float ax = 0.f, ay = 0.f;
    #pragma unroll 8
    for (int v=0; v<32; ++v){
      float wv = wbuf[wid][v][h];
      const float2 f = *reinterpret_cast<const float2*>(&TsL[v*128 + lane*2]);
      ax += wv * f.x; ay += wv * f.y;
    }
    float2 o;
    o.x = eluf(ax*inv + bx);
    o.y = eluf(ay*inv + by);
    *reinterpret_cast<float2*>(&hOut[(size_t)d*128 + lane*2]) = o;
  }
}

// ---------------- node2 fused: 4-edge x 16-lane online softmax ----------------
__global__ __launch_bounds__(256) void k_node2f(
    const int* __restrict__ rowptr, const int* __restrict__ esrc,
    const float* __restrict__ fs, const float* __restrict__ fd,
    const float* __restrict__ pr, float* __restrict__ hOut, int N){
  const float* a2 = pr + 69888;
  const float* b2 = pr + 70016;
  int t = threadIdx.x;
  int wid = t >> 6, lane = t & 63;
  int q = lane & 15, g = lane >> 4;   // lane q holds dims q*8..q*8+7; group g = edge stream
  int d = blockIdx.x*4 + wid;
  if (d >= N) return;
  int r0 = rowptr[d], r1 = rowptr[d+1];
  const float4 a2lo = *reinterpret_cast<const float4*>(a2 + q*8);
  const float4 a2hi = *reinterpret_cast<const float4*>(a2 + q*8 + 4);
  const float4 fdlo = *reinterpret_cast<const float4*>(fd + (size_t)d*128 + q*8);
  const float4 fdhi = *reinterpret_cast<const float4*>(fd + (size_t)d*128 + q*8 + 4);
  float m = -INFINITY, ssum = 0.f;
  float acc[8] = {0.f,0.f,0.f,0.f,0.f,0.f,0.f,0.f};
  for (int i = r0 + g; i < r1; i += 4){
    int s = esrc[i];
    const float4 f0 = *reinterpret_cast<const float4*>(fs + (size_t)s*128 + q*8);
    const float4 f1 = *reinterpret_cast<const float4*>(fs + (size_t)s*128 + q*8 + 4);
    float p = a2lo.x*lrelu(f0.x+fdlo.x) + a2lo.y*lrelu(f0.y+fdlo.y)
            + a2lo.z*lrelu(f0.z+fdlo.z) + a2lo.w*lrelu(f0.w+fdlo.w)
            + a2hi.x*lrelu(f1.x+fdhi.x) + a2hi.y*lrelu(f1.y+fdhi.y)
            + a2hi.z*lrelu(f1.z+fdhi.z) + a2hi.w*lrelu(f1.w+fdhi.w);
    p += __shfl_xor(p, 1); p += __shfl_xor(p, 2);   // head = 4-lane slice
    float mn = fmaxf(m, p);
    float cor = __expf(m - mn);
    float w = __expf(p - mn);
    ssum = ssum*cor + w;
    acc[0]=acc[0]*cor + w*f0.x; acc[1]=acc[1]*cor + w*f0.y;
    acc[2]=acc[2]*cor + w*f0.z; acc[3]=acc[3]*cor + w*f0.w;
    acc[4]=acc[4]*cor + w*f1.x; acc[5]=acc[5]*cor + w*f1.y;
    acc[6]=acc[6]*cor + w*f1.z; acc[7]=acc[7]*cor + w*f1.w;
    m = mn;
  }
  // merge the 4 groups' online states
  #pragma unroll
  for (int off = 16; off <= 32; off <<= 1){
    float mo  = __shfl_xor(m, off);
    float sso = __shfl_xor(ssum, off);
    float ao[8];
    #pragma unroll
    for (int k=0;k<8;++k) ao[k] = __shfl_xor(acc[k], off);
    float mn = fmaxf(m, mo);
    float c1 = (m  > -1e30f) ? __expf(m  - mn) : 0.f;
    float c2 = (mo > -1e30f) ? __expf(mo - mn) : 0.f;
    ssum = ssum*c1 + sso*c2;
    #pragma unroll
    for (int k=0;k<8;++k) acc[k] = acc[k]*c1 + ao[k]*c2;
    m = mn;
  }
  if (g == 0){
    float inv = (ssum > 0.f) ? 1.f/ssum : 0.f;
    float4 o0, o1;
    o0.x = eluf(acc[0]*inv + b2[q*8+0]); o0.y = eluf(acc[1]*inv + b2[q*8+1]);
    o0.z = eluf(acc[2]*inv + b2[q*8+2]); o0.w = eluf(acc[3]*inv + b2[q*8+3]);
    o1.x = eluf(acc[4]*inv + b2[q*8+4]); o1.y = eluf(acc[5]*inv + b2[q*8+5]);
    o1.z = eluf(acc[6]*inv + b2[q*8+6]); o1.w = eluf(acc[7]*inv + b2[q*8+7]);
    *reinterpret_cast<float4*>(hOut + (size_t)d*128 + q*8)     = o0;
    *reinterpret_cast<float4*>(hOut + (size_t)d*128 + q*8 + 4) = o1;
  }
}

// ---------------- node3 fused: 4-edge x 16-lane + head mean + final softmax ----------------
__global__ __launch_bounds__(256) void k_node3f(
    const int* __restrict__ rowptr, const int* __restrict__ esrc,
    const float* __restrict__ el, const float* __restrict__ er, const float* __restrict__ f,
    const float* __restrict__ pr, const int* __restrict__ flag,
    void* __restrict__ out, int N){
  const float* bc = pr + 86784;
  int t = threadIdx.x;
  int wid = t >> 6, lane = t & 63;
  int q = lane & 15, g = lane >> 4;
  int h = q >> 2;                      // head of this lane's dims
  int d = blockIdx.x*4 + wid;
  if (d >= N) return;
  int r0 = rowptr[d], r1 = rowptr[d+1];
  float erh = er[(size_t)d*4 + h];
  float m = -INFINITY, ssum = 0.f;
  float acc[8] = {0.f,0.f,0.f,0.f,0.f,0.f,0.f,0.f};
  for (int i = r0 + g; i < r1; i += 4){
    int s = esrc[i];
    float sc = lrelu(el[(size_t)s*4 + h] + erh);
    const float4 f0 = *reinterpret_cast<const float4*>(f + (size_t)s*128 + q*8);
    const float4 f1 = *reinterpret_cast<const float4*>(f + (size_t)s*128 + q*8 + 4);
    float mn = fmaxf(m, sc);
    float cor = __expf(m - mn);
    float w = __expf(sc - mn);
    ssum = ssum*cor + w;
    acc[0]=acc[0]*cor + w*f0.x; acc[1]=acc[1]*cor + w*f0.y;
    acc[2]=acc[2]*cor + w*f0.z; acc[3]=acc[3]*cor + w*f0.w;
    acc[4]=acc[4]*cor + w*f1.x; acc[5]=acc[5]*cor + w*f1.y;
    acc[6]=acc[6]*cor + w*f1.z; acc[7]=acc[7]*cor + w*f1.w;
    m = mn;
  }
  #pragma unroll
  for (int off = 16; off <= 32; off <<= 1){
    float mo  = __shfl_xor(m, off);
    float sso = __shfl_xor(ssum, off);
    float ao[8];
    #pragma unroll
    for (int k=0;k<8;++k) ao[k] = __shfl_xor(acc[k], off);
    float mn = fmaxf(m, mo);
    float c1 = (m  > -1e30f) ? __expf(m  - mn) : 0.f;
    float c2 = (mo > -1e30f) ? __expf(mo - mn) : 0.f;
    ssum = ssum*c1 + sso*c2;
    #pragma unroll
    for (int k=0;k<8;++k) acc[k] = acc[k]*c1 + ao[k]*c2;
    m = mn;
  }
  float inv = (ssum > 0.f) ? 1.f/ssum : 0.f;
  float v[8];
  #pragma unroll
  for (int k=0;k<8;++k) v[k] = acc[k]*inv + bc[q*8+k];
  // head mean: classes c = (q&3)*8+k live on lanes {c/8, 4+c/8, 8+c/8, 12+c/8}
  #pragma unroll
  for (int k=0;k<8;++k){
    v[k] += __shfl_xor(v[k], 4);
    v[k] += __shfl_xor(v[k], 8);
    v[k] *= 0.25f;
  }
  // softmax over 32 classes spread across 4-lane orbit (xor 1,2), 8 per lane
  float mm = fmaxf(fmaxf(fmaxf(v[0],v[1]),fmaxf(v[2],v[3])),
                   fmaxf(fmaxf(v[4],v[5]),fmaxf(v[6],v[7])));
  mm = fmaxf(mm, __shfl_xor(mm, 1));
  mm = fmaxf(mm, __shfl_xor(mm, 2));
  float ex[8]; float se = 0.f;
  #pragma unroll
  for (int k=0;k<8;++k){ ex[k] = __expf(v[k]-mm); se += ex[k]; }
  se += __shfl_xor(se, 1);
  se += __shfl_xor(se, 2);
  float rs = 1.f/se;
  if (lane < 4){
    if (flag[0]){
      float4 o0 = make_float4(ex[0]*rs, ex[1]*rs, ex[2]*rs, ex[3]*rs);
      float4 o1 = make_float4(ex[4]*rs, ex[5]*rs, ex[6]*rs, ex[7]*rs);
      *reinterpret_cast<float4*>((float*)out + (size_t)d*32 + q*8)     = o0;
      *reinterpret_cast<float4*>((float*)out + (size_t)d*32 + q*8 + 4) = o1;
    } else {
      u32* o = (u32*)out + (size_t)d*16 + q*4;
      o[0] = (u32)f2bf(ex[0]*rs) | ((u32)f2bf(ex[1]*rs) << 16);
      o[1] = (u32)f2bf(ex[2]*rs) | ((u32)f2bf(ex[3]*rs) << 16);
      o[2] = (u32)f2bf(ex[4]*rs) | ((u32)f2bf(ex[5]*rs) << 16);
      o[3] = (u32)f2bf(ex[6]*rs) | ((u32)f2bf(ex[7]*rs) << 16);
    }
  }
}

// ---------------- GEMM: 128-row tile, 512 threads, out = X @ W (optionally two) ----------------
template<bool TWO>
__global__ __launch_bounds__(512) void k_gemm(
    const float* __restrict__ X, const float* __restrict__ Ws, const float* __restrict__ Wd,
    float* __restrict__ outS, float* __restrict__ outD, int N){
  __shared__ float xs[128*128];
  int t = threadIdx.x;
  int row0 = blockIdx.x * 128;
  #pragma unroll
  for (int i = 0; i < 8; ++i){
    int idx = t + i*512;            // float4 index, 0..4095
    int r = idx >> 5;
    int c4 = idx & 31;
    float4 v = make_float4(0.f,0.f,0.f,0.f);
    if (row0 + r < N) v = *reinterpret_cast<const float4*>(X + (size_t)(row0+r)*128 + c4*4);
    *reinterpret_cast<float4*>(&xs[r*128 + c4*4]) = v;
  }
  __syncthreads();
  int rg = t >> 5, jg = t & 31;   // rg 0..15 -> 8 rows each; jg -> 4 cols
  float accS[8][4]; float accD[8][4];
  #pragma unroll
  for (int r=0;r<8;++r)
    #pragma unroll
    for (int c=0;c<4;++c){ accS[r][c]=0.f; accD[r][c]=0.f; }
  const float* xbase = &xs[(rg*8)*128];
  for (int k4 = 0; k4 < 32; ++k4){
    float4 xv[8];
    #pragma unroll
    for (int r=0;r<8;++r) xv[r] = *reinterpret_cast<const float4*>(xbase + r*128 + k4*4);
    #pragma unroll
    for (int kk=0;kk<4;++kk){
      int k = k4*4 + kk;
      float4 ws4 = *reinterpret_cast<const float4*>(Ws + k*128 + jg*4);
      #pragma unroll
      for (int r=0;r<8;++r){
        float xk = (kk==0)?xv[r].x:(kk==1)?xv[r].y:(kk==2)?xv[r].z:xv[r].w;
        accS[r][0] += xk*ws4.x; accS[r][1] += xk*ws4.y;
        accS[r][2] += xk*ws4.z; accS[r][3] += xk*ws4.w;
      }
      if (TWO){
        float4 wd4 = *reinterpret_cast<const float4*>(Wd + k*128 + jg*4);
        #pragma unroll
        for (int r=0;r<8;++r){
          float xk = (kk==0)?xv[r].x:(kk==1)?xv[r].y:(kk==2)?xv[r].z:xv[r].w;
          accD[r][0] += xk*wd4.x; accD[r][1] += xk*wd4.y;
          accD[r][2] += xk*wd4.z; accD[r][3] += xk*wd4.w;
        }
      }
    }
  }
  #pragma unroll
  for (int r=0;r<8;++r){
    int row = row0 + rg*8 + r;
    if (row < N){
      *reinterpret_cast<float4*>(outS + (size_t)row*128 + jg*4) =
          make_float4(accS[r][0],accS[r][1],accS[r][2],accS[r][3]);
      if (TWO){
        *reinterpret_cast<float4*>(outD + (size_t)row*128 + jg*4) =
            make_float4(accD[r][0],accD[r][1],accD[r][2],accD[r][3]);
      }
    }
  }
}

// ---------------- per-node el/er for GAT v1 ----------------
__global__ void k_el(const float* __restrict__ f, const float* __restrict__ pr,
                     float* __restrict__ el, float* __restrict__ er, int N){
  const float* al = pr + 86528;
  const float* ar = pr + 86656;
  int g = blockIdx.x*256 + threadIdx.x;
  if (g >= N*4) return;
  int n = g >> 2, h = g & 3;
  const float4* f4 = reinterpret_cast<const float4*>(f + (size_t)n*128 + h*32);
  const float4* al4 = reinterpret_cast<const float4*>(al + h*32);
  const float4* ar4 = reinterpret_cast<const float4*>(ar + h*32);
  float aL=0.f, aR=0.f;
  #pragma unroll
  for (int q=0;q<8;++q){
    float4 x = f4[q];
    float4 u = al4[q], v = ar4[q];
    aL += u.x*x.x + u.y*x.y + u.z*x.z + u.w*x.w;
    aR += v.x*x.x + v.y*x.y + v.z*x.z + v.w*x.w;
  }
  el[g] = aL; er[g] = aR;
}

extern "C" void kernel_launch(void* const* d_in, const int* in_sizes, int n_in,
                              void* d_out, int out_size, void* d_ws, size_t ws_size,
                              hipStream_t stream){
  const int* in_feat = (const int*)d_in[0];
  const int* src     = (const int*)d_in[1];
  const int* dstA    = (const int*)d_in[2];
  const int N = in_sizes[0];
  const int E = in_sizes[1];

  char* p = (char*)d_ws;
  auto alloc = [&](size_t bytes)->char*{
    char* r = p; p += (bytes + 255) & ~(size_t)255; return r;
  };
  float* big0   = (float*)alloc((size_t)N*128*4);   // H (hist), then fs2, then f3
  float* big1   = (float*)alloc((size_t)N*128*4);   // fd2
  float* big2   = (float*)alloc((size_t)N*128*4);   // h1, then h2
  int*   deg    = (int*)alloc((size_t)N*4);
  int*   rowptr = (int*)alloc((size_t)(N+1)*4);
  int*   cursor = (int*)alloc((size_t)N*4);
  int*   bsum   = (int*)alloc(1024*4);
  int*   boff   = (int*)alloc(1024*4);
  int*   esrc   = (int*)alloc((size_t)E*4);
  float* Ts     = (float*)alloc(4096*4);
  float* Td     = (float*)alloc(4096*4);
  float* S1     = (float*)alloc(4096*4);
  float* Ee     = (float*)alloc(4096*4);
  float* el     = (float*)alloc((size_t)N*4*4);
  float* er     = (float*)alloc((size_t)N*4*4);
  float* parena = (float*)alloc(86912*4);
  int*   flag   = (int*)alloc(256);

  u32* H = (u32*)big0;   // alias: dead before fs2 is written

  // dtype probe + param conversion
  k_probe<<<1,64,0,stream>>>((const u16*)d_in[4], flag);
  Params13 P;
  const int sz[13]  = {4096,16384,16384,128,128,16384,16384,128,128,16384,128,128,128};
  int off = 0;
  for (int t = 0; t < 13; ++t){
    P.src[t] = d_in[3 + t];
    P.n[t] = sz[t];
    P.off[t] = off;
    off += sz[t];
  }
  k_cvt<<<dim3(64,13),256,0,stream>>>(P, flag, parena);

  hipMemsetAsync(H, 0, (size_t)N*32*4, stream);
  int gE = (E + 255)/256;
  int nb = (N + 255)/256;
  k_hist<<<gE,256,0,stream>>>(src, dstA, in_feat, H, E);
  k_bsumH<<<nb,256,0,stream>>>(H, deg, bsum, N);
  k_scanb<<<1,64,0,stream>>>(bsum, boff, rowptr, nb, N);
  k_scan2<<<nb,256,0,stream>>>(deg, boff, rowptr, cursor, N);
  k_scatter<<<gE,256,0,stream>>>(src, dstA, cursor, esrc, E);

  k_tinyA<<<16,256,0,stream>>>(parena, Ts, Td);
  k_tinyB<<<16,256,0,stream>>>(Ts, Td, parena, S1);
  k_tinyC<<<16,256,0,stream>>>(S1, Ee);

  float* h1 = big2;
  int gN32 = (N + 31)/32;
  k_node1h<<<gN32,256,0,stream>>>(H, in_feat, Ts, Ee, parena, h1, N);

  int gG = (N + 127)/128;
  float* fs2 = big0; float* fd2 = big1;   // fs2 overwrites H (H dead now)
  k_gemm<true><<<gG,512,0,stream>>>(h1, parena + 37120, parena + 53504, fs2, fd2, N);

  int gN4 = (N + 3)/4;
  float* h2 = big2;      // h1 consumed by gemm; reuse
  k_node2f<<<gN4,256,0,stream>>>(rowptr, esrc, fs2, fd2, parena, h2, N);

  float* f3 = big0;      // fs2 dead after node2f
  k_gemm<false><<<gG,512,0,stream>>>(h2, parena + 70144, nullptr, f3, nullptr, N);

  int gEl = (int)(((size_t)N*4 + 255)/256);
  k_el<<<gEl,256,0,stream>>>(f3, parena, el, er, N);

  k_node3f<<<gN4,256,0,stream>>>(rowptr, esrc, el, er, f3, parena, flag, d_out, N);
}